// Round 2
// baseline (4145.937 us; speedup 1.0000x reference)
//
#include <hip/hip_runtime.h>
#include <stdint.h>
#include <math.h>

#define BB 8
#define NN 2048
#define KK 32
#define MM (BB*NN)      // 16384 points total
#define LL (MM*KK)      // 524288 gathered rows
static constexpr float EPS = 1e-5f;

// ---------------- workspace layout (float offsets) ----------------
#define OFF_IDX   0                        // int[LL]
#define OFF_Y1    (LL)                     // float[MM*64]
#define OFF_Y2    (OFF_Y1 + MM*64)         // float[MM*64]
#define OFF_U     (OFF_Y2 + MM*64)         // float[MM*128]
#define OFF_V     (OFF_U + MM*128)         // float[MM*128]
#define OFF_F2    (OFF_V + MM*128)         // float[MM*128]
#define OFF_PS    (OFF_F2 + MM*128)        // float[2048*128]
#define OFF_PS2   (OFF_PS + 2048*128)      // float[2048*128]
#define OFF_AB    (OFF_PS2 + 2048*128)     // float[1536]

// ---------------- kNN: per-row iterative min over packed (dist,idx) keys ----------------
// Stores GLOBAL neighbor indices (b*NN + j) so downstream gathers can index the
// flat [MM,128] feature tables directly.
__global__ __launch_bounds__(256) void knn_kernel(const float* __restrict__ x,
                                                  int* __restrict__ idx) {
    __shared__ unsigned long long key[NN];
    __shared__ unsigned long long red[256];
    const int blk = blockIdx.x;
    const int b = blk >> 11;           // /2048
    const int n = blk & (NN - 1);
    const float* xb = x + b * NN * 3;
    const float xn0 = xb[n*3], xn1 = xb[n*3+1], xn2 = xb[n*3+2];
    const float sqn = xn0*xn0 + xn1*xn1 + xn2*xn2;
    for (int j = threadIdx.x; j < NN; j += 256) {
        float x0 = xb[j*3], x1 = xb[j*3+1], x2 = xb[j*3+2];
        float sqj = x0*x0 + x1*x1 + x2*x2;
        float dot = xn0*x0 + xn1*x1 + xn2*x2;
        float d = sqn + sqj - 2.0f*dot;
        d = (j == n) ? 0.0f : fmaxf(d, 0.0f);   // self is exactly 0 in ref; clamp for uint ordering
        key[j] = ((unsigned long long)__float_as_uint(d) << 32) | (unsigned int)j;
    }
    __syncthreads();
    for (int it = 0; it < KK; ++it) {
        unsigned long long m = ~0ULL;
        #pragma unroll
        for (int s = 0; s < NN/256; ++s) {
            unsigned long long k2 = key[threadIdx.x + s*256];
            m = (k2 < m) ? k2 : m;
        }
        red[threadIdx.x] = m;
        __syncthreads();
        for (int off = 128; off > 0; off >>= 1) {
            if (threadIdx.x < off) {
                unsigned long long o = red[threadIdx.x + off];
                if (o < red[threadIdx.x]) red[threadIdx.x] = o;
            }
            __syncthreads();
        }
        if (threadIdx.x == 0) {
            unsigned long long k0 = red[0];
            int j = (int)(unsigned int)(k0 & 0xffffffffu);
            idx[blk*KK + it] = b*NN + j;    // GLOBAL index (bug fix vs round 1)
            key[j] = ~0ULL;                 // remove winner
        }
        __syncthreads();
    }
}

// ---------------- encoder layer 1: y1 = x @ W_e1^T  (3 -> 64) ----------------
__global__ __launch_bounds__(256) void enc1_kernel(const float* __restrict__ x,
                                                   const float* __restrict__ W,
                                                   float* __restrict__ y1) {
    __shared__ float w[192];
    if (threadIdx.x < 192) w[threadIdx.x] = W[threadIdx.x];
    __syncthreads();
    int lin = blockIdx.x*256 + threadIdx.x;   // == row*64 + d
    int row = lin >> 6, d = lin & 63;
    float x0 = x[row*3], x1 = x[row*3+1], x2 = x[row*3+2];
    y1[lin] = x0*w[d*3] + x1*w[d*3+1] + x2*w[d*3+2];
}

// ---------------- per-channel BN stats over M rows -> a,b coeffs ----------------
__global__ __launch_bounds__(256) void colstats_kernel(const float* __restrict__ y,
                                                       int Mrows, int C,
                                                       const float* __restrict__ gamma,
                                                       const float* __restrict__ beta,
                                                       float* __restrict__ a_out,
                                                       float* __restrict__ b_out) {
    __shared__ float rs[256], rs2[256];
    int c = blockIdx.x;
    float s = 0.f, s2 = 0.f;
    for (int r = threadIdx.x; r < Mrows; r += 256) {
        float vv = y[r*C + c];
        s += vv; s2 += vv*vv;
    }
    rs[threadIdx.x] = s; rs2[threadIdx.x] = s2;
    __syncthreads();
    for (int off = 128; off > 0; off >>= 1) {
        if (threadIdx.x < off) {
            rs[threadIdx.x]  += rs[threadIdx.x+off];
            rs2[threadIdx.x] += rs2[threadIdx.x+off];
        }
        __syncthreads();
    }
    if (threadIdx.x == 0) {
        float mean = rs[0] / (float)Mrows;
        float var  = rs2[0] / (float)Mrows - mean*mean;
        float a = gamma[c] * rsqrtf(var + EPS);
        a_out[c] = a;
        b_out[c] = beta[c] - mean*a;
    }
}

// ---------------- encoder layer 2: y2 = relu(bn(y1)) @ W_e2^T (64 -> 64) ----------------
__global__ __launch_bounds__(256) void enc2_kernel(const float* __restrict__ y1,
                                                   const float* __restrict__ a,
                                                   const float* __restrict__ b,
                                                   const float* __restrict__ W,
                                                   float* __restrict__ y2) {
    __shared__ float wt[4096];   // transposed: wt[c*64+d] = W[d*64+c]
    __shared__ float f[256];     // 4 rows x 64 ch, bn_relu'd
    for (int i = threadIdx.x; i < 4096; i += 256)
        wt[(i & 63)*64 + (i >> 6)] = W[i];
    int lin = blockIdx.x*256 + threadIdx.x;
    int c0 = threadIdx.x & 63;
    f[threadIdx.x] = fmaxf(a[c0]*y1[lin] + b[c0], 0.0f);
    __syncthreads();
    int rloc = threadIdx.x >> 6, d = threadIdx.x & 63;
    const float* fr = f + rloc*64;
    float acc = 0.f;
    #pragma unroll 8
    for (int c = 0; c < 64; ++c) acc += fr[c] * wt[c*64 + d];
    y2[lin] = acc;
}

// ---------------- u/v transform: u = f@Wl^T, v = f@(Wr-Wl)^T ----------------
template<int CIN, bool APPLY_BN>
__global__ __launch_bounds__(256) void uv_kernel(const float* __restrict__ fin,
                                                 const float* __restrict__ a,
                                                 const float* __restrict__ b,
                                                 const float* __restrict__ W,  // 128 x (2*CIN)
                                                 float* __restrict__ u,
                                                 float* __restrict__ v) {
    __shared__ float f[32*CIN];
    const int r0 = blockIdx.x * 32;
    for (int i = threadIdx.x; i < 32*CIN; i += 256) {
        float val = fin[r0*CIN + i];
        if (APPLY_BN) {
            int c = i & (CIN-1);
            val = fmaxf(a[c]*val + b[c], 0.0f);
        }
        f[i] = val;
    }
    __syncthreads();
    const int d  = threadIdx.x & 127;
    const int rg = threadIdx.x >> 7;   // 0..1
    float uacc[16], vacc[16];
    #pragma unroll
    for (int r = 0; r < 16; ++r) { uacc[r] = 0.f; vacc[r] = 0.f; }
    const float* wl = W + d*2*CIN;
    const float* wr = wl + CIN;
    for (int c = 0; c < CIN; ++c) {
        float wlv = wl[c];
        float wdv = wr[c] - wlv;
        #pragma unroll
        for (int r = 0; r < 16; ++r) {
            float xv = f[(rg*16 + r)*CIN + c];
            uacc[r] += xv*wlv;
            vacc[r] += xv*wdv;
        }
    }
    #pragma unroll
    for (int r = 0; r < 16; ++r) {
        int row = r0 + rg*16 + r;
        u[row*128 + d] = uacc[r];
        v[row*128 + d] = vacc[r];
    }
}

// ---------------- stats of e = u[idx] + v over all (b,n,k), per channel ----------------
__global__ __launch_bounds__(256) void estats_kernel(const float* __restrict__ u,
                                                     const float* __restrict__ v,
                                                     const int* __restrict__ idx,
                                                     float* __restrict__ pS,
                                                     float* __restrict__ pS2) {
    __shared__ float red[256];
    const int c = threadIdx.x & 127;
    const int g = threadIdx.x >> 7;    // 0..1
    const int row0 = blockIdx.x * 256;
    float s = 0.f, s2 = 0.f;
    for (int r = 0; r < 128; ++r) {
        int row = row0 + r*2 + g;
        int n = row >> 5;              // global point index
        int j = idx[row];              // global neighbor index
        float e = u[j*128 + c] + v[n*128 + c];
        s += e; s2 += e*e;
    }
    red[threadIdx.x] = s;
    __syncthreads();
    if (g == 0) pS[blockIdx.x*128 + c] = red[c] + red[128 + c];
    __syncthreads();
    red[threadIdx.x] = s2;
    __syncthreads();
    if (g == 0) pS2[blockIdx.x*128 + c] = red[c] + red[128 + c];
}

// ---------------- finalize BN coeffs from block partials (double accum) ----------------
__global__ __launch_bounds__(128) void reduce_ab_kernel(const float* __restrict__ pS,
                                                        const float* __restrict__ pS2,
                                                        int nblk, float count,
                                                        const float* __restrict__ gamma,
                                                        const float* __restrict__ beta,
                                                        float* __restrict__ a_out,
                                                        float* __restrict__ b_out) {
    int c = threadIdx.x;
    double s = 0.0, s2 = 0.0;
    for (int i = 0; i < nblk; ++i) {
        s  += (double)pS[i*128 + c];
        s2 += (double)pS2[i*128 + c];
    }
    double mean = s / (double)count;
    double var  = s2 / (double)count - mean*mean;
    float a = gamma[c] * (float)(1.0 / sqrt(var + (double)EPS));
    a_out[c] = a;
    b_out[c] = beta[c] - (float)mean * a;
}

// ---------------- local_op core: act = relu(bn1(u[idx]+v)); h2 = act @ W2^T ----------------
// STATS=true : accumulate per-channel sum/sumsq of h2 into partials
// STATS=false: apply bn2+relu, max over k, write out[point][128]
template<bool STATS>
__global__ __launch_bounds__(256) void local_kernel(const float* __restrict__ u,
                                                    const float* __restrict__ v,
                                                    const int* __restrict__ idx,
                                                    const float* __restrict__ a1,
                                                    const float* __restrict__ b1,
                                                    const float* __restrict__ W2,   // 128x128
                                                    const float* __restrict__ a2,
                                                    const float* __restrict__ b2,
                                                    float* __restrict__ pS,
                                                    float* __restrict__ pS2,
                                                    float* __restrict__ outp) {
    __shared__ float wt[128*132];   // wt[c*132+d] = W2[d*128+c]  (pad 132 kills bank conflicts)
    __shared__ float act[128*36];   // act[c*36+r], r=0..31        (pad 36, 16B-aligned rows)
    __shared__ float red[8*128];
    const int t = threadIdx.x;
    for (int i = t; i < 16384; i += 256) {
        int d = i >> 7, c = i & 127;
        wt[c*132 + d] = W2[i];
    }
    const int rq = t >> 5;    // 0..7 -> rows 4rq..4rq+3
    const int dq = t & 31;    // 0..31 -> cols 4dq..4dq+3
    float s[4]  = {0,0,0,0};
    float s2[4] = {0,0,0,0};
    float a2v[4], b2v[4];
    if (!STATS) {
        #pragma unroll
        for (int i = 0; i < 4; ++i) { a2v[i] = a2[4*dq+i]; b2v[i] = b2[4*dq+i]; }
    }
    const int p0 = blockIdx.x * 8;
    for (int g = 0; g < 8; ++g) {
        const int p = p0 + g;
        __syncthreads();   // act (and first-iter wt) safe to overwrite / fully staged
        #pragma unroll
        for (int i = 0; i < 16; ++i) {
            int lin = t + i*256;
            int r = lin >> 7, c = lin & 127;
            int j = idx[p*32 + r];      // global neighbor index
            float e = u[j*128 + c] + v[p*128 + c];
            act[c*36 + r] = fmaxf(a1[c]*e + b1[c], 0.0f);
        }
        __syncthreads();
        float h[4][4];
        #pragma unroll
        for (int i = 0; i < 4; ++i)
            #pragma unroll
            for (int k = 0; k < 4; ++k) h[i][k] = 0.f;
        #pragma unroll 4
        for (int c = 0; c < 128; ++c) {
            float4 av = *(const float4*)&act[c*36 + 4*rq];
            float4 wv = *(const float4*)&wt[c*132 + 4*dq];
            float aa[4] = {av.x, av.y, av.z, av.w};
            float ww[4] = {wv.x, wv.y, wv.z, wv.w};
            #pragma unroll
            for (int i = 0; i < 4; ++i)
                #pragma unroll
                for (int k = 0; k < 4; ++k)
                    h[i][k] += aa[i]*ww[k];
        }
        if (STATS) {
            #pragma unroll
            for (int k = 0; k < 4; ++k) {
                s[k]  += h[0][k] + h[1][k] + h[2][k] + h[3][k];
                s2[k] += h[0][k]*h[0][k] + h[1][k]*h[1][k] + h[2][k]*h[2][k] + h[3][k]*h[3][k];
            }
        } else {
            float m[4];
            #pragma unroll
            for (int k = 0; k < 4; ++k) {
                float v0 = fmaxf(a2v[k]*h[0][k] + b2v[k], 0.0f);
                float v1 = fmaxf(a2v[k]*h[1][k] + b2v[k], 0.0f);
                float v2 = fmaxf(a2v[k]*h[2][k] + b2v[k], 0.0f);
                float v3 = fmaxf(a2v[k]*h[3][k] + b2v[k], 0.0f);
                m[k] = fmaxf(fmaxf(v0, v1), fmaxf(v2, v3));
            }
            *(float4*)&red[rq*128 + 4*dq] = make_float4(m[0], m[1], m[2], m[3]);
            __syncthreads();
            if (t < 128) {
                float mx = red[t];
                #pragma unroll
                for (int q = 1; q < 8; ++q) mx = fmaxf(mx, red[q*128 + t]);
                outp[p*128 + t] = mx;
            }
            // next loop-top __syncthreads() protects red reuse
        }
    }
    if (STATS) {
        __syncthreads();
        *(float4*)&red[rq*128 + 4*dq] = make_float4(s[0], s[1], s[2], s[3]);
        __syncthreads();
        if (t < 128) {
            float tot = red[t];
            #pragma unroll
            for (int q = 1; q < 8; ++q) tot += red[q*128 + t];
            pS[blockIdx.x*128 + t] = tot;
        }
        __syncthreads();
        *(float4*)&red[rq*128 + 4*dq] = make_float4(s2[0], s2[1], s2[2], s2[3]);
        __syncthreads();
        if (t < 128) {
            float tot = red[t];
            #pragma unroll
            for (int q = 1; q < 8; ++q) tot += red[q*128 + t];
            pS2[blockIdx.x*128 + t] = tot;
        }
    }
}

// ---------------- host launcher ----------------
extern "C" void kernel_launch(void* const* d_in, const int* in_sizes, int n_in,
                              void* d_out, int out_size, void* d_ws, size_t ws_size,
                              hipStream_t stream) {
    const float* x     = (const float*)d_in[0];
    const float* W_e1  = (const float*)d_in[1];
    const float* g_e1  = (const float*)d_in[2];
    const float* b_e1  = (const float*)d_in[3];
    const float* W_e2  = (const float*)d_in[4];
    const float* g_e2  = (const float*)d_in[5];
    const float* b_e2  = (const float*)d_in[6];
    const float* W_l1a = (const float*)d_in[7];
    const float* g_l1a = (const float*)d_in[8];
    const float* b_l1a = (const float*)d_in[9];
    const float* W_l1b = (const float*)d_in[10];
    const float* g_l1b = (const float*)d_in[11];
    const float* b_l1b = (const float*)d_in[12];
    const float* W_l2a = (const float*)d_in[13];
    const float* g_l2a = (const float*)d_in[14];
    const float* b_l2a = (const float*)d_in[15];
    const float* W_l2b = (const float*)d_in[16];
    const float* g_l2b = (const float*)d_in[17];
    const float* b_l2b = (const float*)d_in[18];

    float* ws   = (float*)d_ws;
    int*   idx  = (int*)(ws + OFF_IDX);
    float* y1   = ws + OFF_Y1;
    float* y2   = ws + OFF_Y2;
    float* u    = ws + OFF_U;
    float* v    = ws + OFF_V;
    float* f2   = ws + OFF_F2;
    float* pS   = ws + OFF_PS;
    float* pS2  = ws + OFF_PS2;
    float* ab   = ws + OFF_AB;
    float *a_e1 = ab,        *be1 = ab + 128,
          *a_e2 = ab + 256,  *be2 = ab + 384,
          *a_1a = ab + 512,  *b_1a = ab + 640,
          *a_1b = ab + 768,  *b_1b = ab + 896,
          *a_2a = ab + 1024, *b_2a = ab + 1152,
          *a_2b = ab + 1280, *b_2b = ab + 1408;

    knn_kernel<<<dim3(MM), dim3(256), 0, stream>>>(x, idx);

    enc1_kernel<<<dim3(MM*64/256), dim3(256), 0, stream>>>(x, W_e1, y1);
    colstats_kernel<<<dim3(64), dim3(256), 0, stream>>>(y1, MM, 64, g_e1, b_e1, a_e1, be1);
    enc2_kernel<<<dim3(MM*64/256), dim3(256), 0, stream>>>(y1, a_e1, be1, W_e2, y2);
    colstats_kernel<<<dim3(64), dim3(256), 0, stream>>>(y2, MM, 64, g_e2, b_e2, a_e2, be2);

    // ---- local_op 1 ----
    uv_kernel<64, true><<<dim3(MM/32), dim3(256), 0, stream>>>(y2, a_e2, be2, W_l1a, u, v);
    estats_kernel<<<dim3(LL/256), dim3(256), 0, stream>>>(u, v, idx, pS, pS2);
    reduce_ab_kernel<<<dim3(1), dim3(128), 0, stream>>>(pS, pS2, LL/256, (float)LL, g_l1a, b_l1a, a_1a, b_1a);
    local_kernel<true><<<dim3(MM/8), dim3(256), 0, stream>>>(u, v, idx, a_1a, b_1a, W_l1b,
                                                             nullptr, nullptr, pS, pS2, nullptr);
    reduce_ab_kernel<<<dim3(1), dim3(128), 0, stream>>>(pS, pS2, MM/8, (float)LL, g_l1b, b_l1b, a_1b, b_1b);
    local_kernel<false><<<dim3(MM/8), dim3(256), 0, stream>>>(u, v, idx, a_1a, b_1a, W_l1b,
                                                              a_1b, b_1b, nullptr, nullptr, f2);

    // ---- local_op 2 ----
    uv_kernel<128, false><<<dim3(MM/32), dim3(256), 0, stream>>>(f2, nullptr, nullptr, W_l2a, u, v);
    estats_kernel<<<dim3(LL/256), dim3(256), 0, stream>>>(u, v, idx, pS, pS2);
    reduce_ab_kernel<<<dim3(1), dim3(128), 0, stream>>>(pS, pS2, LL/256, (float)LL, g_l2a, b_l2a, a_2a, b_2a);
    local_kernel<true><<<dim3(MM/8), dim3(256), 0, stream>>>(u, v, idx, a_2a, b_2a, W_l2b,
                                                             nullptr, nullptr, pS, pS2, nullptr);
    reduce_ab_kernel<<<dim3(1), dim3(128), 0, stream>>>(pS, pS2, MM/8, (float)LL, g_l2b, b_l2b, a_2b, b_2b);
    local_kernel<false><<<dim3(MM/8), dim3(256), 0, stream>>>(u, v, idx, a_2a, b_2a, W_l2b,
                                                              a_2b, b_2b, nullptr, nullptr, (float*)d_out);
}

// Round 3
// 823.774 us; speedup vs baseline: 5.0329x; 5.0329x over previous
//
#include <hip/hip_runtime.h>
#include <stdint.h>
#include <math.h>

#define BB 8
#define NN 2048
#define KK 32
#define MM (BB*NN)      // 16384 points total
#define LL (MM*KK)      // 524288 gathered rows
static constexpr float EPS = 1e-5f;

typedef short  short4v __attribute__((ext_vector_type(4)));
typedef short  short8v __attribute__((ext_vector_type(8)));
typedef float  f32x4   __attribute__((ext_vector_type(4)));

__device__ inline short f2bf(float f) {   // RNE float->bf16
    unsigned u = __float_as_uint(f);
    u += 0x7fffu + ((u >> 16) & 1u);
    return (short)(u >> 16);
}

// ---------------- workspace layout (float offsets) ----------------
#define OFF_IDX   0                        // int[LL]
#define OFF_Y1    (LL)                     // float[MM*64]
#define OFF_Y2    (OFF_Y1 + MM*64)         // float[MM*64]
#define OFF_U     (OFF_Y2 + MM*64)         // float[MM*128]
#define OFF_V     (OFF_U + MM*128)         // float[MM*128]
#define OFF_F2    (OFF_V + MM*128)         // float[MM*128]
#define OFF_PS    (OFF_F2 + MM*128)        // float[2048*128]
#define OFF_PS2   (OFF_PS + 2048*128)      // float[2048*128]
#define OFF_AB    (OFF_PS2 + 2048*128)     // float[1536]

// ---------------- kNN: per-row iterative min over packed (dist,idx) keys ----------------
__global__ __launch_bounds__(256) void knn_kernel(const float* __restrict__ x,
                                                  int* __restrict__ idx) {
    __shared__ unsigned long long key[NN];
    __shared__ unsigned long long red[256];
    const int blk = blockIdx.x;
    const int b = blk >> 11;           // /2048
    const int n = blk & (NN - 1);
    const float* xb = x + b * NN * 3;
    const float xn0 = xb[n*3], xn1 = xb[n*3+1], xn2 = xb[n*3+2];
    const float sqn = xn0*xn0 + xn1*xn1 + xn2*xn2;
    for (int j = threadIdx.x; j < NN; j += 256) {
        float x0 = xb[j*3], x1 = xb[j*3+1], x2 = xb[j*3+2];
        float sqj = x0*x0 + x1*x1 + x2*x2;
        float dot = xn0*x0 + xn1*x1 + xn2*x2;
        float d = sqn + sqj - 2.0f*dot;
        d = (j == n) ? 0.0f : fmaxf(d, 0.0f);
        key[j] = ((unsigned long long)__float_as_uint(d) << 32) | (unsigned int)j;
    }
    __syncthreads();
    for (int it = 0; it < KK; ++it) {
        unsigned long long m = ~0ULL;
        #pragma unroll
        for (int s = 0; s < NN/256; ++s) {
            unsigned long long k2 = key[threadIdx.x + s*256];
            m = (k2 < m) ? k2 : m;
        }
        red[threadIdx.x] = m;
        __syncthreads();
        for (int off = 128; off > 0; off >>= 1) {
            if (threadIdx.x < off) {
                unsigned long long o = red[threadIdx.x + off];
                if (o < red[threadIdx.x]) red[threadIdx.x] = o;
            }
            __syncthreads();
        }
        if (threadIdx.x == 0) {
            unsigned long long k0 = red[0];
            int j = (int)(unsigned int)(k0 & 0xffffffffu);
            idx[blk*KK + it] = b*NN + j;    // GLOBAL index
            key[j] = ~0ULL;
        }
        __syncthreads();
    }
}

// ---------------- encoder layer 1: y1 = x @ W_e1^T  (3 -> 64) ----------------
__global__ __launch_bounds__(256) void enc1_kernel(const float* __restrict__ x,
                                                   const float* __restrict__ W,
                                                   float* __restrict__ y1) {
    __shared__ float w[192];
    if (threadIdx.x < 192) w[threadIdx.x] = W[threadIdx.x];
    __syncthreads();
    int lin = blockIdx.x*256 + threadIdx.x;
    int row = lin >> 6, d = lin & 63;
    float x0 = x[row*3], x1 = x[row*3+1], x2 = x[row*3+2];
    y1[lin] = x0*w[d*3] + x1*w[d*3+1] + x2*w[d*3+2];
}

// ---------------- per-channel BN stats over M rows -> a,b coeffs ----------------
__global__ __launch_bounds__(256) void colstats_kernel(const float* __restrict__ y,
                                                       int Mrows, int C,
                                                       const float* __restrict__ gamma,
                                                       const float* __restrict__ beta,
                                                       float* __restrict__ a_out,
                                                       float* __restrict__ b_out) {
    __shared__ float rs[256], rs2[256];
    int c = blockIdx.x;
    float s = 0.f, s2 = 0.f;
    for (int r = threadIdx.x; r < Mrows; r += 256) {
        float vv = y[r*C + c];
        s += vv; s2 += vv*vv;
    }
    rs[threadIdx.x] = s; rs2[threadIdx.x] = s2;
    __syncthreads();
    for (int off = 128; off > 0; off >>= 1) {
        if (threadIdx.x < off) {
            rs[threadIdx.x]  += rs[threadIdx.x+off];
            rs2[threadIdx.x] += rs2[threadIdx.x+off];
        }
        __syncthreads();
    }
    if (threadIdx.x == 0) {
        float mean = rs[0] / (float)Mrows;
        float var  = rs2[0] / (float)Mrows - mean*mean;
        float a = gamma[c] * rsqrtf(var + EPS);
        a_out[c] = a;
        b_out[c] = beta[c] - mean*a;
    }
}

// ---------------- encoder layer 2: y2 = relu(bn(y1)) @ W_e2^T (64 -> 64) ----------------
__global__ __launch_bounds__(256) void enc2_kernel(const float* __restrict__ y1,
                                                   const float* __restrict__ a,
                                                   const float* __restrict__ b,
                                                   const float* __restrict__ W,
                                                   float* __restrict__ y2) {
    __shared__ float wt[4096];   // transposed: wt[c*64+d] = W[d*64+c]
    __shared__ float f[256];
    for (int i = threadIdx.x; i < 4096; i += 256)
        wt[(i & 63)*64 + (i >> 6)] = W[i];
    int lin = blockIdx.x*256 + threadIdx.x;
    int c0 = threadIdx.x & 63;
    f[threadIdx.x] = fmaxf(a[c0]*y1[lin] + b[c0], 0.0f);
    __syncthreads();
    int rloc = threadIdx.x >> 6, d = threadIdx.x & 63;
    const float* fr = f + rloc*64;
    float acc = 0.f;
    #pragma unroll 8
    for (int c = 0; c < 64; ++c) acc += fr[c] * wt[c*64 + d];
    y2[lin] = acc;
}

// ---------------- u/v transform: u = f@Wl^T, v = f@(Wr-Wl)^T ----------------
template<int CIN, bool APPLY_BN>
__global__ __launch_bounds__(256) void uv_kernel(const float* __restrict__ fin,
                                                 const float* __restrict__ a,
                                                 const float* __restrict__ b,
                                                 const float* __restrict__ W,  // 128 x (2*CIN)
                                                 float* __restrict__ u,
                                                 float* __restrict__ v) {
    __shared__ float f[32*CIN];
    const int r0 = blockIdx.x * 32;
    for (int i = threadIdx.x; i < 32*CIN; i += 256) {
        float val = fin[r0*CIN + i];
        if (APPLY_BN) {
            int c = i & (CIN-1);
            val = fmaxf(a[c]*val + b[c], 0.0f);
        }
        f[i] = val;
    }
    __syncthreads();
    const int d  = threadIdx.x & 127;
    const int rg = threadIdx.x >> 7;   // 0..1
    float uacc[16], vacc[16];
    #pragma unroll
    for (int r = 0; r < 16; ++r) { uacc[r] = 0.f; vacc[r] = 0.f; }
    const float* wl = W + d*2*CIN;
    const float* wr = wl + CIN;
    for (int c = 0; c < CIN; ++c) {
        float wlv = wl[c];
        float wdv = wr[c] - wlv;
        #pragma unroll
        for (int r = 0; r < 16; ++r) {
            float xv = f[(rg*16 + r)*CIN + c];
            uacc[r] += xv*wlv;
            vacc[r] += xv*wdv;
        }
    }
    #pragma unroll
    for (int r = 0; r < 16; ++r) {
        int row = r0 + rg*16 + r;
        u[row*128 + d] = uacc[r];
        v[row*128 + d] = vacc[r];
    }
}

// ---------------- stats of e = u[idx] + v over all (b,n,k), per channel ----------------
__global__ __launch_bounds__(256) void estats_kernel(const float* __restrict__ u,
                                                     const float* __restrict__ v,
                                                     const int* __restrict__ idx,
                                                     float* __restrict__ pS,
                                                     float* __restrict__ pS2) {
    __shared__ float red[256];
    const int c = threadIdx.x & 127;
    const int g = threadIdx.x >> 7;
    const int row0 = blockIdx.x * 256;
    float s = 0.f, s2 = 0.f;
    for (int r = 0; r < 128; ++r) {
        int row = row0 + r*2 + g;
        int n = row >> 5;
        int j = idx[row];
        float e = u[j*128 + c] + v[n*128 + c];
        s += e; s2 += e*e;
    }
    red[threadIdx.x] = s;
    __syncthreads();
    if (g == 0) pS[blockIdx.x*128 + c] = red[c] + red[128 + c];
    __syncthreads();
    red[threadIdx.x] = s2;
    __syncthreads();
    if (g == 0) pS2[blockIdx.x*128 + c] = red[c] + red[128 + c];
}

// ---------------- finalize BN coeffs: 128 blocks (one per channel) ----------------
__global__ __launch_bounds__(256) void reduce_ab_kernel(const float* __restrict__ pS,
                                                        const float* __restrict__ pS2,
                                                        int nblk, float count,
                                                        const float* __restrict__ gamma,
                                                        const float* __restrict__ beta,
                                                        float* __restrict__ a_out,
                                                        float* __restrict__ b_out) {
    __shared__ double rs[256], rs2[256];
    const int c = blockIdx.x;
    const int t = threadIdx.x;
    double s = 0.0, s2 = 0.0;
    for (int i = t; i < nblk; i += 256) {
        s  += (double)pS [i*128 + c];
        s2 += (double)pS2[i*128 + c];
    }
    rs[t] = s; rs2[t] = s2;
    __syncthreads();
    for (int off = 128; off > 0; off >>= 1) {
        if (t < off) { rs[t] += rs[t+off]; rs2[t] += rs2[t+off]; }
        __syncthreads();
    }
    if (t == 0) {
        double mean = rs[0] / (double)count;
        double var  = rs2[0] / (double)count - mean*mean;
        float a = gamma[c] * (float)(1.0 / sqrt(var + (double)EPS));
        a_out[c] = a;
        b_out[c] = beta[c] - (float)mean * a;
    }
}

// ---------------- fold bn1 into u,v (in place): u'=a*u, v'=a*v+b ----------------
__global__ __launch_bounds__(256) void scale_uv_kernel(float* __restrict__ u,
                                                       float* __restrict__ v,
                                                       const float* __restrict__ a,
                                                       const float* __restrict__ b) {
    int i = blockIdx.x*256 + threadIdx.x;   // float4 index over MM*32
    int c = (i & 31) * 4;
    float4 av = *(const float4*)&a[c];
    float4 bv = *(const float4*)&b[c];
    float4 uu = ((float4*)u)[i];
    float4 vv = ((float4*)v)[i];
    uu.x *= av.x; uu.y *= av.y; uu.z *= av.z; uu.w *= av.w;
    vv.x = av.x*vv.x + bv.x; vv.y = av.y*vv.y + bv.y;
    vv.z = av.z*vv.z + bv.z; vv.w = av.w*vv.w + bv.w;
    ((float4*)u)[i] = uu;
    ((float4*)v)[i] = vv;
}

// ---------------- local_op core via MFMA bf16 ----------------
// act[r,c] = relu(u'[idx[p,r],c] + v'[p,c]) -> bf16, h2 = act @ W2^T via
// mfma_f32_16x16x32_bf16. STATS: per-channel sum/sumsq of h2 -> pS/pS2.
// OUT: out[p,d] = relu(a2[d]*max_r(h2[r,d]) + b2[d])   (a2>0 -> max/bn commute)
template<bool STATS>
__global__ __launch_bounds__(256) void local_mfma_kernel(
        const float* __restrict__ u, const float* __restrict__ v,
        const int* __restrict__ idx,
        const float* __restrict__ W2,          // 128x128 row-major [d][c]
        const float* __restrict__ a2, const float* __restrict__ b2,
        float* __restrict__ pS, float* __restrict__ pS2,
        float* __restrict__ outp) {
    __shared__ short wlds[128*136];     // bf16 W2 [d][c], pad 136 (row stride 272B)
    __shared__ short alds[2][32*136];   // bf16 act [r][c], double-buffered
    const int t  = threadIdx.x;
    const int l  = t & 63;
    const int w  = t >> 6;       // wave 0..3 -> output cols 32w..32w+31
    const int lr = l & 15;
    const int kg = l >> 4;       // 0..3

    // stage W2 as bf16 (coalesced float4 reads)
    for (int i = t*4; i < 16384; i += 1024) {
        float4 wv = *(const float4*)&W2[i];
        int d = i >> 7, c = i & 127;
        short4v pk;
        pk.x = f2bf(wv.x); pk.y = f2bf(wv.y); pk.z = f2bf(wv.z); pk.w = f2bf(wv.w);
        *(short4v*)&wlds[d*136 + c] = pk;
    }

    float a2v[2], b2v[2];
    if (!STATS) {
        #pragma unroll
        for (int ct = 0; ct < 2; ++ct) {
            int d = w*32 + ct*16 + lr;
            a2v[ct] = a2[d]; b2v[ct] = b2[d];
        }
    }
    float sacc[2] = {0.f, 0.f}, s2acc[2] = {0.f, 0.f};

    const int p0 = blockIdx.x * 8;
    const int sr = t >> 3;          // staging row 0..31
    const int sc = (t & 7) * 16;    // staging col base

    // stage point 0 into buffer 0
    {
        int j = idx[p0*KK + sr];
        const float* up = u + (size_t)j*128 + sc;
        const float* vp = v + (size_t)p0*128 + sc;
        short* dst = &alds[0][sr*136 + sc];
        #pragma unroll
        for (int q = 0; q < 2; ++q) {
            float4 u0 = *(const float4*)(up + q*8);
            float4 u1 = *(const float4*)(up + q*8 + 4);
            float4 v0 = *(const float4*)(vp + q*8);
            float4 v1 = *(const float4*)(vp + q*8 + 4);
            short8v pk;
            pk[0] = f2bf(fmaxf(u0.x + v0.x, 0.f));
            pk[1] = f2bf(fmaxf(u0.y + v0.y, 0.f));
            pk[2] = f2bf(fmaxf(u0.z + v0.z, 0.f));
            pk[3] = f2bf(fmaxf(u0.w + v0.w, 0.f));
            pk[4] = f2bf(fmaxf(u1.x + v1.x, 0.f));
            pk[5] = f2bf(fmaxf(u1.y + v1.y, 0.f));
            pk[6] = f2bf(fmaxf(u1.z + v1.z, 0.f));
            pk[7] = f2bf(fmaxf(u1.w + v1.w, 0.f));
            *(short8v*)(dst + q*8) = pk;
        }
    }
    __syncthreads();

    for (int g = 0; g < 8; ++g) {
        const int p = p0 + g;
        if (g < 7) {   // prefetch-stage next point into the other buffer
            int pn = p + 1;
            int j = idx[pn*KK + sr];
            const float* up = u + (size_t)j*128 + sc;
            const float* vp = v + (size_t)pn*128 + sc;
            short* dst = &alds[(g+1) & 1][sr*136 + sc];
            #pragma unroll
            for (int q = 0; q < 2; ++q) {
                float4 u0 = *(const float4*)(up + q*8);
                float4 u1 = *(const float4*)(up + q*8 + 4);
                float4 v0 = *(const float4*)(vp + q*8);
                float4 v1 = *(const float4*)(vp + q*8 + 4);
                short8v pk;
                pk[0] = f2bf(fmaxf(u0.x + v0.x, 0.f));
                pk[1] = f2bf(fmaxf(u0.y + v0.y, 0.f));
                pk[2] = f2bf(fmaxf(u0.z + v0.z, 0.f));
                pk[3] = f2bf(fmaxf(u0.w + v0.w, 0.f));
                pk[4] = f2bf(fmaxf(u1.x + v1.x, 0.f));
                pk[5] = f2bf(fmaxf(u1.y + v1.y, 0.f));
                pk[6] = f2bf(fmaxf(u1.z + v1.z, 0.f));
                pk[7] = f2bf(fmaxf(u1.w + v1.w, 0.f));
                *(short8v*)(dst + q*8) = pk;
            }
        }
        // compute on buffer g&1
        const short* ab = alds[g & 1];
        f32x4 acc[2][2];
        #pragma unroll
        for (int rt = 0; rt < 2; ++rt)
            #pragma unroll
            for (int ct = 0; ct < 2; ++ct)
                acc[rt][ct] = (f32x4){0.f, 0.f, 0.f, 0.f};
        #pragma unroll
        for (int kk = 0; kk < 4; ++kk) {
            const int ko = kk*32 + kg*8;
            short8v a0 = *(const short8v*)&ab[lr*136 + ko];
            short8v a1 = *(const short8v*)&ab[(16 + lr)*136 + ko];
            short8v b0 = *(const short8v*)&wlds[(w*32 + lr)*136 + ko];
            short8v b1 = *(const short8v*)&wlds[(w*32 + 16 + lr)*136 + ko];
            acc[0][0] = __builtin_amdgcn_mfma_f32_16x16x32_bf16(a0, b0, acc[0][0], 0, 0, 0);
            acc[1][0] = __builtin_amdgcn_mfma_f32_16x16x32_bf16(a1, b0, acc[1][0], 0, 0, 0);
            acc[0][1] = __builtin_amdgcn_mfma_f32_16x16x32_bf16(a0, b1, acc[0][1], 0, 0, 0);
            acc[1][1] = __builtin_amdgcn_mfma_f32_16x16x32_bf16(a1, b1, acc[1][1], 0, 0, 0);
        }
        if (STATS) {
            #pragma unroll
            for (int ct = 0; ct < 2; ++ct) {
                float s = 0.f, q = 0.f;
                #pragma unroll
                for (int rt = 0; rt < 2; ++rt)
                    #pragma unroll
                    for (int e = 0; e < 4; ++e) {
                        float h = acc[rt][ct][e];
                        s += h; q += h*h;
                    }
                sacc[ct] += s; s2acc[ct] += q;
            }
        } else {
            #pragma unroll
            for (int ct = 0; ct < 2; ++ct) {
                float m = acc[0][ct][0];
                #pragma unroll
                for (int rt = 0; rt < 2; ++rt)
                    #pragma unroll
                    for (int e = 0; e < 4; ++e)
                        m = fmaxf(m, acc[rt][ct][e]);
                m = fmaxf(m, __shfl_xor(m, 16, 64));
                m = fmaxf(m, __shfl_xor(m, 32, 64));
                if (l < 16) {
                    float val = fmaxf(a2v[ct]*m + b2v[ct], 0.f);
                    outp[(size_t)p*128 + w*32 + ct*16 + lr] = val;
                }
            }
        }
        __syncthreads();
    }
    if (STATS) {
        #pragma unroll
        for (int ct = 0; ct < 2; ++ct) {
            float s = sacc[ct], q = s2acc[ct];
            s += __shfl_xor(s, 16, 64); s += __shfl_xor(s, 32, 64);
            q += __shfl_xor(q, 16, 64); q += __shfl_xor(q, 32, 64);
            if (l < 16) {
                pS [blockIdx.x*128 + w*32 + ct*16 + lr] = s;
                pS2[blockIdx.x*128 + w*32 + ct*16 + lr] = q;
            }
        }
    }
}

// ---------------- host launcher ----------------
extern "C" void kernel_launch(void* const* d_in, const int* in_sizes, int n_in,
                              void* d_out, int out_size, void* d_ws, size_t ws_size,
                              hipStream_t stream) {
    const float* x     = (const float*)d_in[0];
    const float* W_e1  = (const float*)d_in[1];
    const float* g_e1  = (const float*)d_in[2];
    const float* b_e1  = (const float*)d_in[3];
    const float* W_e2  = (const float*)d_in[4];
    const float* g_e2  = (const float*)d_in[5];
    const float* b_e2  = (const float*)d_in[6];
    const float* W_l1a = (const float*)d_in[7];
    const float* g_l1a = (const float*)d_in[8];
    const float* b_l1a = (const float*)d_in[9];
    const float* W_l1b = (const float*)d_in[10];
    const float* g_l1b = (const float*)d_in[11];
    const float* b_l1b = (const float*)d_in[12];
    const float* W_l2a = (const float*)d_in[13];
    const float* g_l2a = (const float*)d_in[14];
    const float* b_l2a = (const float*)d_in[15];
    const float* W_l2b = (const float*)d_in[16];
    const float* g_l2b = (const float*)d_in[17];
    const float* b_l2b = (const float*)d_in[18];

    float* ws   = (float*)d_ws;
    int*   idx  = (int*)(ws + OFF_IDX);
    float* y1   = ws + OFF_Y1;
    float* y2   = ws + OFF_Y2;
    float* u    = ws + OFF_U;
    float* v    = ws + OFF_V;
    float* f2   = ws + OFF_F2;
    float* pS   = ws + OFF_PS;
    float* pS2  = ws + OFF_PS2;
    float* ab   = ws + OFF_AB;
    float *a_e1 = ab,        *be1 = ab + 128,
          *a_e2 = ab + 256,  *be2 = ab + 384,
          *a_1a = ab + 512,  *b_1a = ab + 640,
          *a_1b = ab + 768,  *b_1b = ab + 896,
          *a_2a = ab + 1024, *b_2a = ab + 1152,
          *a_2b = ab + 1280, *b_2b = ab + 1408;

    knn_kernel<<<dim3(MM), dim3(256), 0, stream>>>(x, idx);

    enc1_kernel<<<dim3(MM*64/256), dim3(256), 0, stream>>>(x, W_e1, y1);
    colstats_kernel<<<dim3(64), dim3(256), 0, stream>>>(y1, MM, 64, g_e1, b_e1, a_e1, be1);
    enc2_kernel<<<dim3(MM*64/256), dim3(256), 0, stream>>>(y1, a_e1, be1, W_e2, y2);
    colstats_kernel<<<dim3(64), dim3(256), 0, stream>>>(y2, MM, 64, g_e2, b_e2, a_e2, be2);

    // ---- local_op 1 ----
    uv_kernel<64, true><<<dim3(MM/32), dim3(256), 0, stream>>>(y2, a_e2, be2, W_l1a, u, v);
    estats_kernel<<<dim3(LL/256), dim3(256), 0, stream>>>(u, v, idx, pS, pS2);
    reduce_ab_kernel<<<dim3(128), dim3(256), 0, stream>>>(pS, pS2, LL/256, (float)LL, g_l1a, b_l1a, a_1a, b_1a);
    scale_uv_kernel<<<dim3(MM*32/256), dim3(256), 0, stream>>>(u, v, a_1a, b_1a);
    local_mfma_kernel<true><<<dim3(MM/8), dim3(256), 0, stream>>>(u, v, idx, W_l1b,
                                                                  nullptr, nullptr, pS, pS2, nullptr);
    reduce_ab_kernel<<<dim3(128), dim3(256), 0, stream>>>(pS, pS2, MM/8, (float)LL, g_l1b, b_l1b, a_1b, b_1b);
    local_mfma_kernel<false><<<dim3(MM/8), dim3(256), 0, stream>>>(u, v, idx, W_l1b,
                                                                   a_1b, b_1b, nullptr, nullptr, f2);

    // ---- local_op 2 ----
    uv_kernel<128, false><<<dim3(MM/32), dim3(256), 0, stream>>>(f2, nullptr, nullptr, W_l2a, u, v);
    estats_kernel<<<dim3(LL/256), dim3(256), 0, stream>>>(u, v, idx, pS, pS2);
    reduce_ab_kernel<<<dim3(128), dim3(256), 0, stream>>>(pS, pS2, LL/256, (float)LL, g_l2a, b_l2a, a_2a, b_2a);
    scale_uv_kernel<<<dim3(MM*32/256), dim3(256), 0, stream>>>(u, v, a_2a, b_2a);
    local_mfma_kernel<true><<<dim3(MM/8), dim3(256), 0, stream>>>(u, v, idx, W_l2b,
                                                                  nullptr, nullptr, pS, pS2, nullptr);
    reduce_ab_kernel<<<dim3(128), dim3(256), 0, stream>>>(pS, pS2, MM/8, (float)LL, g_l2b, b_l2b, a_2b, b_2b);
    local_mfma_kernel<false><<<dim3(MM/8), dim3(256), 0, stream>>>(u, v, idx, W_l2b,
                                                                   a_2b, b_2b, nullptr, nullptr, (float*)d_out);
}

// Round 4
// 697.404 us; speedup vs baseline: 5.9448x; 1.1812x over previous
//
#include <hip/hip_runtime.h>
#include <stdint.h>
#include <math.h>

#define BB 8
#define NN 2048
#define KK 32
#define MM (BB*NN)      // 16384 points total
#define LL (MM*KK)      // 524288 gathered rows
static constexpr float EPS = 1e-5f;

typedef short  short4v __attribute__((ext_vector_type(4)));
typedef short  short8v __attribute__((ext_vector_type(8)));
typedef float  f32x4   __attribute__((ext_vector_type(4)));

__device__ inline short f2bf(float f) {   // RNE float->bf16
    unsigned u = __float_as_uint(f);
    u += 0x7fffu + ((u >> 16) & 1u);
    return (short)(u >> 16);
}

// ---------------- workspace layout (float offsets) ----------------
#define OFF_IDX   0                        // int[LL]
#define OFF_Y1    (LL)                     // float[MM*64]
#define OFF_Y2    (OFF_Y1 + MM*64)         // float[MM*64]
#define OFF_U     (OFF_Y2 + MM*64)         // float[MM*128]
#define OFF_V     (OFF_U + MM*128)         // float[MM*128]
#define OFF_F2    (OFF_V + MM*128)         // float[MM*128]
#define OFF_PS    (OFF_F2 + MM*128)        // float[2048*128]
#define OFF_PS2   (OFF_PS + 2048*128)      // float[2048*128]
#define OFF_AB    (OFF_PS2 + 2048*128)     // float[1536]

// ---------------- kNN: wave-per-query, barrier-free top-32 extraction -------
// Each wave owns one query. Lane owns candidates j = s*64+lane (s=0..31),
// keeps dist bits in a private LDS row and a running min key (dist<<32|j)
// in registers. 32 iterations: 64-lane shfl min-reduce -> winner; collective
// rescan of the winner lane's 32 slots rebuilds only that lane's min.
// Key order (dist,idx) ascending == jax.lax.top_k(-d) with stable ties.
__global__ __launch_bounds__(256) void knn_kernel(const float* __restrict__ x,
                                                  int* __restrict__ idx_out) {
    __shared__ float xs[NN], ys[NN], zs[NN];
    __shared__ unsigned int dlds[4][64][33];   // stride 33: 2-way banks (free)
    const int t    = threadIdx.x;
    const int lane = t & 63;
    const int wv   = t >> 6;
    const int q    = blockIdx.x * 4 + wv;      // global query id
    const int b    = q >> 11;                  // batch (uniform per block: 2048%4==0)
    const int n    = q & (NN - 1);

    const float* xb = x + (size_t)b * NN * 3;
    for (int i = t; i < NN*3; i += 256) {
        float val = xb[i];
        int j = i / 3, c = i - j*3;
        if (c == 0) xs[j] = val; else if (c == 1) ys[j] = val; else zs[j] = val;
    }
    __syncthreads();

    const float qx = xs[n], qy = ys[n], qz = zs[n];
    const float sqn = qx*qx + qy*qy + qz*qz;

    unsigned long long lmin = ~0ULL;
    #pragma unroll
    for (int s = 0; s < 32; ++s) {
        int j = s*64 + lane;
        float x0 = xs[j], x1 = ys[j], x2 = zs[j];
        float sqj = x0*x0 + x1*x1 + x2*x2;
        float dot = qx*x0 + qy*x1 + qz*x2;
        float d = sqn + sqj - 2.0f*dot;
        d = (j == n) ? 0.0f : fmaxf(d, 0.0f);
        unsigned int db = __float_as_uint(d);
        dlds[wv][lane][s] = db;
        unsigned long long key = ((unsigned long long)db << 32) | (unsigned int)j;
        lmin = key < lmin ? key : lmin;
    }

    const int out_base = q * KK;
    const int gbase    = b * NN;
    #pragma unroll 1
    for (int it = 0; it < KK; ++it) {
        // 64-lane min reduce of per-lane mins
        unsigned long long wm = lmin;
        #pragma unroll
        for (int dd = 1; dd < 64; dd <<= 1) {
            unsigned long long o = __shfl_xor(wm, dd, 64);
            wm = o < wm ? o : wm;
        }
        int wjl = (int)(unsigned int)wm;        // local winner index j
        if (lane == 0) idx_out[out_base + it] = gbase + wjl;
        int wl = wjl & 63;                      // winner lane
        int sw = wjl >> 6;                      // winner slot
        // remove for future iterations (masked this iteration explicitly)
        if (lane == wl) dlds[wv][wl][sw] = 0xFFFFFFFFu;
        // collective rescan of winner lane's 32 slots (2 lanes per slot)
        int rl = lane & 31;
        unsigned int db = dlds[wv][wl][rl];
        unsigned long long rk = ((unsigned long long)db << 32) | (unsigned int)(rl*64 + wl);
        if (rl == sw) rk = ~0ULL;
        #pragma unroll
        for (int dd = 1; dd < 32; dd <<= 1) {
            unsigned long long o = __shfl_xor(rk, dd, 64);
            rk = o < rk ? o : rk;
        }
        if (lane == wl) lmin = rk;
    }
}

// ---------------- encoder layer 1: y1 = x @ W_e1^T  (3 -> 64) ----------------
__global__ __launch_bounds__(256) void enc1_kernel(const float* __restrict__ x,
                                                   const float* __restrict__ W,
                                                   float* __restrict__ y1) {
    __shared__ float w[192];
    if (threadIdx.x < 192) w[threadIdx.x] = W[threadIdx.x];
    __syncthreads();
    int lin = blockIdx.x*256 + threadIdx.x;
    int row = lin >> 6, d = lin & 63;
    float x0 = x[row*3], x1 = x[row*3+1], x2 = x[row*3+2];
    y1[lin] = x0*w[d*3] + x1*w[d*3+1] + x2*w[d*3+2];
}

// ---------------- per-channel BN stats over M rows -> a,b coeffs ----------------
__global__ __launch_bounds__(256) void colstats_kernel(const float* __restrict__ y,
                                                       int Mrows, int C,
                                                       const float* __restrict__ gamma,
                                                       const float* __restrict__ beta,
                                                       float* __restrict__ a_out,
                                                       float* __restrict__ b_out) {
    __shared__ float rs[256], rs2[256];
    int c = blockIdx.x;
    float s = 0.f, s2 = 0.f;
    for (int r = threadIdx.x; r < Mrows; r += 256) {
        float vv = y[r*C + c];
        s += vv; s2 += vv*vv;
    }
    rs[threadIdx.x] = s; rs2[threadIdx.x] = s2;
    __syncthreads();
    for (int off = 128; off > 0; off >>= 1) {
        if (threadIdx.x < off) {
            rs[threadIdx.x]  += rs[threadIdx.x+off];
            rs2[threadIdx.x] += rs2[threadIdx.x+off];
        }
        __syncthreads();
    }
    if (threadIdx.x == 0) {
        float mean = rs[0] / (float)Mrows;
        float var  = rs2[0] / (float)Mrows - mean*mean;
        float a = gamma[c] * rsqrtf(var + EPS);
        a_out[c] = a;
        b_out[c] = beta[c] - mean*a;
    }
}

// ---------------- encoder layer 2: y2 = relu(bn(y1)) @ W_e2^T (64 -> 64) ----------------
__global__ __launch_bounds__(256) void enc2_kernel(const float* __restrict__ y1,
                                                   const float* __restrict__ a,
                                                   const float* __restrict__ b,
                                                   const float* __restrict__ W,
                                                   float* __restrict__ y2) {
    __shared__ float wt[4096];   // transposed: wt[c*64+d] = W[d*64+c]
    __shared__ float f[256];
    for (int i = threadIdx.x; i < 4096; i += 256)
        wt[(i & 63)*64 + (i >> 6)] = W[i];
    int lin = blockIdx.x*256 + threadIdx.x;
    int c0 = threadIdx.x & 63;
    f[threadIdx.x] = fmaxf(a[c0]*y1[lin] + b[c0], 0.0f);
    __syncthreads();
    int rloc = threadIdx.x >> 6, d = threadIdx.x & 63;
    const float* fr = f + rloc*64;
    float acc = 0.f;
    #pragma unroll 8
    for (int c = 0; c < 64; ++c) acc += fr[c] * wt[c*64 + d];
    y2[lin] = acc;
}

// ---------------- u/v transform: u = f@Wl^T, v = f@(Wr-Wl)^T ----------------
template<int CIN, bool APPLY_BN>
__global__ __launch_bounds__(256) void uv_kernel(const float* __restrict__ fin,
                                                 const float* __restrict__ a,
                                                 const float* __restrict__ b,
                                                 const float* __restrict__ W,  // 128 x (2*CIN)
                                                 float* __restrict__ u,
                                                 float* __restrict__ v) {
    __shared__ float f[32*CIN];
    const int r0 = blockIdx.x * 32;
    for (int i = threadIdx.x; i < 32*CIN; i += 256) {
        float val = fin[r0*CIN + i];
        if (APPLY_BN) {
            int c = i & (CIN-1);
            val = fmaxf(a[c]*val + b[c], 0.0f);
        }
        f[i] = val;
    }
    __syncthreads();
    const int d  = threadIdx.x & 127;
    const int rg = threadIdx.x >> 7;   // 0..1
    float uacc[16], vacc[16];
    #pragma unroll
    for (int r = 0; r < 16; ++r) { uacc[r] = 0.f; vacc[r] = 0.f; }
    const float* wl = W + d*2*CIN;
    const float* wr = wl + CIN;
    for (int c = 0; c < CIN; ++c) {
        float wlv = wl[c];
        float wdv = wr[c] - wlv;
        #pragma unroll
        for (int r = 0; r < 16; ++r) {
            float xv = f[(rg*16 + r)*CIN + c];
            uacc[r] += xv*wlv;
            vacc[r] += xv*wdv;
        }
    }
    #pragma unroll
    for (int r = 0; r < 16; ++r) {
        int row = r0 + rg*16 + r;
        u[row*128 + d] = uacc[r];
        v[row*128 + d] = vacc[r];
    }
}

// ---------------- stats of e = u[idx] + v over all (b,n,k), per channel ----------------
__global__ __launch_bounds__(256) void estats_kernel(const float* __restrict__ u,
                                                     const float* __restrict__ v,
                                                     const int* __restrict__ idx,
                                                     float* __restrict__ pS,
                                                     float* __restrict__ pS2) {
    __shared__ float red[256];
    const int c = threadIdx.x & 127;
    const int g = threadIdx.x >> 7;
    const int row0 = blockIdx.x * 256;
    float s = 0.f, s2 = 0.f;
    for (int r = 0; r < 128; ++r) {
        int row = row0 + r*2 + g;
        int n = row >> 5;
        int j = idx[row];
        float e = u[j*128 + c] + v[n*128 + c];
        s += e; s2 += e*e;
    }
    red[threadIdx.x] = s;
    __syncthreads();
    if (g == 0) pS[blockIdx.x*128 + c] = red[c] + red[128 + c];
    __syncthreads();
    red[threadIdx.x] = s2;
    __syncthreads();
    if (g == 0) pS2[blockIdx.x*128 + c] = red[c] + red[128 + c];
}

// ---------------- finalize BN coeffs: 128 blocks (one per channel) ----------------
__global__ __launch_bounds__(256) void reduce_ab_kernel(const float* __restrict__ pS,
                                                        const float* __restrict__ pS2,
                                                        int nblk, float count,
                                                        const float* __restrict__ gamma,
                                                        const float* __restrict__ beta,
                                                        float* __restrict__ a_out,
                                                        float* __restrict__ b_out) {
    __shared__ double rs[256], rs2[256];
    const int c = blockIdx.x;
    const int t = threadIdx.x;
    double s = 0.0, s2 = 0.0;
    for (int i = t; i < nblk; i += 256) {
        s  += (double)pS [i*128 + c];
        s2 += (double)pS2[i*128 + c];
    }
    rs[t] = s; rs2[t] = s2;
    __syncthreads();
    for (int off = 128; off > 0; off >>= 1) {
        if (t < off) { rs[t] += rs[t+off]; rs2[t] += rs2[t+off]; }
        __syncthreads();
    }
    if (t == 0) {
        double mean = rs[0] / (double)count;
        double var  = rs2[0] / (double)count - mean*mean;
        float a = gamma[c] * (float)(1.0 / sqrt(var + (double)EPS));
        a_out[c] = a;
        b_out[c] = beta[c] - (float)mean * a;
    }
}

// ---------------- fold bn1 into u,v (in place): u'=a*u, v'=a*v+b ----------------
__global__ __launch_bounds__(256) void scale_uv_kernel(float* __restrict__ u,
                                                       float* __restrict__ v,
                                                       const float* __restrict__ a,
                                                       const float* __restrict__ b) {
    int i = blockIdx.x*256 + threadIdx.x;   // float4 index over MM*32
    int c = (i & 31) * 4;
    float4 av = *(const float4*)&a[c];
    float4 bv = *(const float4*)&b[c];
    float4 uu = ((float4*)u)[i];
    float4 vv = ((float4*)v)[i];
    uu.x *= av.x; uu.y *= av.y; uu.z *= av.z; uu.w *= av.w;
    vv.x = av.x*vv.x + bv.x; vv.y = av.y*vv.y + bv.y;
    vv.z = av.z*vv.z + bv.z; vv.w = av.w*vv.w + bv.w;
    ((float4*)u)[i] = uu;
    ((float4*)v)[i] = vv;
}

// ---------------- local_op core via MFMA bf16 ----------------
template<bool STATS>
__global__ __launch_bounds__(256) void local_mfma_kernel(
        const float* __restrict__ u, const float* __restrict__ v,
        const int* __restrict__ idx,
        const float* __restrict__ W2,          // 128x128 row-major [d][c]
        const float* __restrict__ a2, const float* __restrict__ b2,
        float* __restrict__ pS, float* __restrict__ pS2,
        float* __restrict__ outp) {
    __shared__ short wlds[128*136];     // bf16 W2 [d][c], pad 136
    __shared__ short alds[2][32*136];   // bf16 act [r][c], double-buffered
    const int t  = threadIdx.x;
    const int l  = t & 63;
    const int w  = t >> 6;       // wave 0..3 -> output cols 32w..32w+31
    const int lr = l & 15;
    const int kg = l >> 4;       // 0..3

    for (int i = t*4; i < 16384; i += 1024) {
        float4 wv = *(const float4*)&W2[i];
        int d = i >> 7, c = i & 127;
        short4v pk;
        pk.x = f2bf(wv.x); pk.y = f2bf(wv.y); pk.z = f2bf(wv.z); pk.w = f2bf(wv.w);
        *(short4v*)&wlds[d*136 + c] = pk;
    }

    float a2v[2], b2v[2];
    if (!STATS) {
        #pragma unroll
        for (int ct = 0; ct < 2; ++ct) {
            int d = w*32 + ct*16 + lr;
            a2v[ct] = a2[d]; b2v[ct] = b2[d];
        }
    }
    float sacc[2] = {0.f, 0.f}, s2acc[2] = {0.f, 0.f};

    const int p0 = blockIdx.x * 8;
    const int sr = t >> 3;          // staging row 0..31
    const int sc = (t & 7) * 16;    // staging col base

    {
        int j = idx[p0*KK + sr];
        const float* up = u + (size_t)j*128 + sc;
        const float* vp = v + (size_t)p0*128 + sc;
        short* dst = &alds[0][sr*136 + sc];
        #pragma unroll
        for (int q = 0; q < 2; ++q) {
            float4 u0 = *(const float4*)(up + q*8);
            float4 u1 = *(const float4*)(up + q*8 + 4);
            float4 v0 = *(const float4*)(vp + q*8);
            float4 v1 = *(const float4*)(vp + q*8 + 4);
            short8v pk;
            pk[0] = f2bf(fmaxf(u0.x + v0.x, 0.f));
            pk[1] = f2bf(fmaxf(u0.y + v0.y, 0.f));
            pk[2] = f2bf(fmaxf(u0.z + v0.z, 0.f));
            pk[3] = f2bf(fmaxf(u0.w + v0.w, 0.f));
            pk[4] = f2bf(fmaxf(u1.x + v1.x, 0.f));
            pk[5] = f2bf(fmaxf(u1.y + v1.y, 0.f));
            pk[6] = f2bf(fmaxf(u1.z + v1.z, 0.f));
            pk[7] = f2bf(fmaxf(u1.w + v1.w, 0.f));
            *(short8v*)(dst + q*8) = pk;
        }
    }
    __syncthreads();

    for (int g = 0; g < 8; ++g) {
        const int p = p0 + g;
        if (g < 7) {
            int pn = p + 1;
            int j = idx[pn*KK + sr];
            const float* up = u + (size_t)j*128 + sc;
            const float* vp = v + (size_t)pn*128 + sc;
            short* dst = &alds[(g+1) & 1][sr*136 + sc];
            #pragma unroll
            for (int q = 0; q < 2; ++q) {
                float4 u0 = *(const float4*)(up + q*8);
                float4 u1 = *(const float4*)(up + q*8 + 4);
                float4 v0 = *(const float4*)(vp + q*8);
                float4 v1 = *(const float4*)(vp + q*8 + 4);
                short8v pk;
                pk[0] = f2bf(fmaxf(u0.x + v0.x, 0.f));
                pk[1] = f2bf(fmaxf(u0.y + v0.y, 0.f));
                pk[2] = f2bf(fmaxf(u0.z + v0.z, 0.f));
                pk[3] = f2bf(fmaxf(u0.w + v0.w, 0.f));
                pk[4] = f2bf(fmaxf(u1.x + v1.x, 0.f));
                pk[5] = f2bf(fmaxf(u1.y + v1.y, 0.f));
                pk[6] = f2bf(fmaxf(u1.z + v1.z, 0.f));
                pk[7] = f2bf(fmaxf(u1.w + v1.w, 0.f));
                *(short8v*)(dst + q*8) = pk;
            }
        }
        const short* ab = alds[g & 1];
        f32x4 acc[2][2];
        #pragma unroll
        for (int rt = 0; rt < 2; ++rt)
            #pragma unroll
            for (int ct = 0; ct < 2; ++ct)
                acc[rt][ct] = (f32x4){0.f, 0.f, 0.f, 0.f};
        #pragma unroll
        for (int kk = 0; kk < 4; ++kk) {
            const int ko = kk*32 + kg*8;
            short8v a0 = *(const short8v*)&ab[lr*136 + ko];
            short8v a1 = *(const short8v*)&ab[(16 + lr)*136 + ko];
            short8v b0 = *(const short8v*)&wlds[(w*32 + lr)*136 + ko];
            short8v b1 = *(const short8v*)&wlds[(w*32 + 16 + lr)*136 + ko];
            acc[0][0] = __builtin_amdgcn_mfma_f32_16x16x32_bf16(a0, b0, acc[0][0], 0, 0, 0);
            acc[1][0] = __builtin_amdgcn_mfma_f32_16x16x32_bf16(a1, b0, acc[1][0], 0, 0, 0);
            acc[0][1] = __builtin_amdgcn_mfma_f32_16x16x32_bf16(a0, b1, acc[0][1], 0, 0, 0);
            acc[1][1] = __builtin_amdgcn_mfma_f32_16x16x32_bf16(a1, b1, acc[1][1], 0, 0, 0);
        }
        if (STATS) {
            #pragma unroll
            for (int ct = 0; ct < 2; ++ct) {
                float s = 0.f, q = 0.f;
                #pragma unroll
                for (int rt = 0; rt < 2; ++rt)
                    #pragma unroll
                    for (int e = 0; e < 4; ++e) {
                        float h = acc[rt][ct][e];
                        s += h; q += h*h;
                    }
                sacc[ct] += s; s2acc[ct] += q;
            }
        } else {
            #pragma unroll
            for (int ct = 0; ct < 2; ++ct) {
                float m = acc[0][ct][0];
                #pragma unroll
                for (int rt = 0; rt < 2; ++rt)
                    #pragma unroll
                    for (int e = 0; e < 4; ++e)
                        m = fmaxf(m, acc[rt][ct][e]);
                m = fmaxf(m, __shfl_xor(m, 16, 64));
                m = fmaxf(m, __shfl_xor(m, 32, 64));
                if (l < 16) {
                    float val = fmaxf(a2v[ct]*m + b2v[ct], 0.f);
                    outp[(size_t)p*128 + w*32 + ct*16 + lr] = val;
                }
            }
        }
        __syncthreads();
    }
    if (STATS) {
        #pragma unroll
        for (int ct = 0; ct < 2; ++ct) {
            float s = sacc[ct], q = s2acc[ct];
            s += __shfl_xor(s, 16, 64); s += __shfl_xor(s, 32, 64);
            q += __shfl_xor(q, 16, 64); q += __shfl_xor(q, 32, 64);
            if (l < 16) {
                pS [blockIdx.x*128 + w*32 + ct*16 + lr] = s;
                pS2[blockIdx.x*128 + w*32 + ct*16 + lr] = q;
            }
        }
    }
}

// ---------------- host launcher ----------------
extern "C" void kernel_launch(void* const* d_in, const int* in_sizes, int n_in,
                              void* d_out, int out_size, void* d_ws, size_t ws_size,
                              hipStream_t stream) {
    const float* x     = (const float*)d_in[0];
    const float* W_e1  = (const float*)d_in[1];
    const float* g_e1  = (const float*)d_in[2];
    const float* b_e1  = (const float*)d_in[3];
    const float* W_e2  = (const float*)d_in[4];
    const float* g_e2  = (const float*)d_in[5];
    const float* b_e2  = (const float*)d_in[6];
    const float* W_l1a = (const float*)d_in[7];
    const float* g_l1a = (const float*)d_in[8];
    const float* b_l1a = (const float*)d_in[9];
    const float* W_l1b = (const float*)d_in[10];
    const float* g_l1b = (const float*)d_in[11];
    const float* b_l1b = (const float*)d_in[12];
    const float* W_l2a = (const float*)d_in[13];
    const float* g_l2a = (const float*)d_in[14];
    const float* b_l2a = (const float*)d_in[15];
    const float* W_l2b = (const float*)d_in[16];
    const float* g_l2b = (const float*)d_in[17];
    const float* b_l2b = (const float*)d_in[18];

    float* ws   = (float*)d_ws;
    int*   idx  = (int*)(ws + OFF_IDX);
    float* y1   = ws + OFF_Y1;
    float* y2   = ws + OFF_Y2;
    float* u    = ws + OFF_U;
    float* v    = ws + OFF_V;
    float* f2   = ws + OFF_F2;
    float* pS   = ws + OFF_PS;
    float* pS2  = ws + OFF_PS2;
    float* ab   = ws + OFF_AB;
    float *a_e1 = ab,        *be1 = ab + 128,
          *a_e2 = ab + 256,  *be2 = ab + 384,
          *a_1a = ab + 512,  *b_1a = ab + 640,
          *a_1b = ab + 768,  *b_1b = ab + 896,
          *a_2a = ab + 1024, *b_2a = ab + 1152,
          *a_2b = ab + 1280, *b_2b = ab + 1408;

    knn_kernel<<<dim3(MM/4), dim3(256), 0, stream>>>(x, idx);

    enc1_kernel<<<dim3(MM*64/256), dim3(256), 0, stream>>>(x, W_e1, y1);
    colstats_kernel<<<dim3(64), dim3(256), 0, stream>>>(y1, MM, 64, g_e1, b_e1, a_e1, be1);
    enc2_kernel<<<dim3(MM*64/256), dim3(256), 0, stream>>>(y1, a_e1, be1, W_e2, y2);
    colstats_kernel<<<dim3(64), dim3(256), 0, stream>>>(y2, MM, 64, g_e2, b_e2, a_e2, be2);

    // ---- local_op 1 ----
    uv_kernel<64, true><<<dim3(MM/32), dim3(256), 0, stream>>>(y2, a_e2, be2, W_l1a, u, v);
    estats_kernel<<<dim3(LL/256), dim3(256), 0, stream>>>(u, v, idx, pS, pS2);
    reduce_ab_kernel<<<dim3(128), dim3(256), 0, stream>>>(pS, pS2, LL/256, (float)LL, g_l1a, b_l1a, a_1a, b_1a);
    scale_uv_kernel<<<dim3(MM*32/256), dim3(256), 0, stream>>>(u, v, a_1a, b_1a);
    local_mfma_kernel<true><<<dim3(MM/8), dim3(256), 0, stream>>>(u, v, idx, W_l1b,
                                                                  nullptr, nullptr, pS, pS2, nullptr);
    reduce_ab_kernel<<<dim3(128), dim3(256), 0, stream>>>(pS, pS2, MM/8, (float)LL, g_l1b, b_l1b, a_1b, b_1b);
    local_mfma_kernel<false><<<dim3(MM/8), dim3(256), 0, stream>>>(u, v, idx, W_l1b,
                                                                   a_1b, b_1b, nullptr, nullptr, f2);

    // ---- local_op 2 ----
    uv_kernel<128, false><<<dim3(MM/32), dim3(256), 0, stream>>>(f2, nullptr, nullptr, W_l2a, u, v);
    estats_kernel<<<dim3(LL/256), dim3(256), 0, stream>>>(u, v, idx, pS, pS2);
    reduce_ab_kernel<<<dim3(128), dim3(256), 0, stream>>>(pS, pS2, LL/256, (float)LL, g_l2a, b_l2a, a_2a, b_2a);
    scale_uv_kernel<<<dim3(MM*32/256), dim3(256), 0, stream>>>(u, v, a_2a, b_2a);
    local_mfma_kernel<true><<<dim3(MM/8), dim3(256), 0, stream>>>(u, v, idx, W_l2b,
                                                                  nullptr, nullptr, pS, pS2, nullptr);
    reduce_ab_kernel<<<dim3(128), dim3(256), 0, stream>>>(pS, pS2, MM/8, (float)LL, g_l2b, b_l2b, a_2b, b_2b);
    local_mfma_kernel<false><<<dim3(MM/8), dim3(256), 0, stream>>>(u, v, idx, W_l2b,
                                                                   a_2b, b_2b, nullptr, nullptr, (float*)d_out);
}

// Round 5
// 578.852 us; speedup vs baseline: 7.1623x; 1.2048x over previous
//
#include <hip/hip_runtime.h>
#include <stdint.h>
#include <math.h>

#define BB 8
#define NN 2048
#define KK 32
#define MM (BB*NN)      // 16384 points total
#define LL (MM*KK)      // 524288 gathered rows
#define NBLK 2048       // partial-stat blocks (estats grid == local grid == 2048)
static constexpr float EPS = 1e-5f;

typedef short  short4v __attribute__((ext_vector_type(4)));
typedef short  short8v __attribute__((ext_vector_type(8)));
typedef float  f32x4   __attribute__((ext_vector_type(4)));
typedef unsigned int u32;
typedef unsigned short u16;

__device__ inline short f2bf(float f) {   // RNE float->bf16
    unsigned u = __float_as_uint(f);
    u += 0x7fffu + ((u >> 16) & 1u);
    return (short)(u >> 16);
}

// ---------------- workspace layout (float offsets; u/v regions half-used as bf16) ----
#define OFF_IDX   0                        // int[LL]
#define OFF_Y1    (LL)                     // float[MM*64]
#define OFF_Y2    (OFF_Y1 + MM*64)         // float[MM*64]
#define OFF_U     (OFF_Y2 + MM*64)         // u16[MM*128] (in float[MM*128] region)
#define OFF_V     (OFF_U + MM*128)         // u16[MM*128]
#define OFF_F2    (OFF_V + MM*128)         // float[MM*128]
#define OFF_PS    (OFF_F2 + MM*128)        // float[128*NBLK] channel-major
#define OFF_PS2   (OFF_PS + 2048*128)      // float[128*NBLK]
#define OFF_AB    (OFF_PS2 + 2048*128)     // float[1536]

// ---------------- kNN: wave-per-query, barrier-free, x read via L1/L2 ----------------
// Lane owns candidates j = s*64+lane; dist bits kept in a private LDS row
// (stride 33 -> 2-way bank alias, free) and a running min key (dist<<32|j)
// in registers. 32 iterations: 64-lane shfl min-reduce -> winner; collective
// rescan of the winner lane's 32 slots rebuilds only that lane's min.
__global__ __launch_bounds__(256) void knn_kernel(const float* __restrict__ x,
                                                  int* __restrict__ idx_out) {
    __shared__ unsigned int dlds[4][64][33];   // 33.8 KB -> 4 blocks/CU
    const int t    = threadIdx.x;
    const int lane = t & 63;
    const int wv   = t >> 6;
    const int q    = blockIdx.x * 4 + wv;
    const int b    = q >> 11;
    const int n    = q & (NN - 1);

    const float* xb = x + (size_t)b * NN * 3;
    const float qx = xb[n*3], qy = xb[n*3+1], qz = xb[n*3+2];
    const float sqn = qx*qx + qy*qy + qz*qz;

    unsigned long long lmin = ~0ULL;
    #pragma unroll 4
    for (int s = 0; s < 32; ++s) {
        int j = s*64 + lane;
        const float* pj = xb + j*3;
        float x0 = pj[0], x1 = pj[1], x2 = pj[2];
        float sqj = x0*x0 + x1*x1 + x2*x2;
        float dot = qx*x0 + qy*x1 + qz*x2;
        float d = sqn + sqj - 2.0f*dot;
        d = (j == n) ? 0.0f : fmaxf(d, 0.0f);
        unsigned int db = __float_as_uint(d);
        dlds[wv][lane][s] = db;
        unsigned long long key = ((unsigned long long)db << 32) | (unsigned int)j;
        lmin = key < lmin ? key : lmin;
    }

    const int out_base = q * KK;
    const int gbase    = b * NN;
    #pragma unroll 1
    for (int it = 0; it < KK; ++it) {
        unsigned long long wm = lmin;
        #pragma unroll
        for (int dd = 1; dd < 64; dd <<= 1) {
            unsigned long long o = __shfl_xor(wm, dd, 64);
            wm = o < wm ? o : wm;
        }
        int wjl = (int)(unsigned int)wm;
        if (lane == 0) idx_out[out_base + it] = gbase + wjl;
        int wl = wjl & 63;
        int sw = wjl >> 6;
        if (lane == wl) dlds[wv][wl][sw] = 0xFFFFFFFFu;
        int rl = lane & 31;
        unsigned int db = dlds[wv][wl][rl];
        unsigned long long rk = ((unsigned long long)db << 32) | (unsigned int)(rl*64 + wl);
        if (rl == sw) rk = ~0ULL;
        #pragma unroll
        for (int dd = 1; dd < 32; dd <<= 1) {
            unsigned long long o = __shfl_xor(rk, dd, 64);
            rk = o < rk ? o : rk;
        }
        if (lane == wl) lmin = rk;
    }
}

// ---------------- encoder layer 1: y1 = x @ W_e1^T  (3 -> 64) ----------------
__global__ __launch_bounds__(256) void enc1_kernel(const float* __restrict__ x,
                                                   const float* __restrict__ W,
                                                   float* __restrict__ y1) {
    __shared__ float w[192];
    if (threadIdx.x < 192) w[threadIdx.x] = W[threadIdx.x];
    __syncthreads();
    int lin = blockIdx.x*256 + threadIdx.x;
    int row = lin >> 6, d = lin & 63;
    float x0 = x[row*3], x1 = x[row*3+1], x2 = x[row*3+2];
    y1[lin] = x0*w[d*3] + x1*w[d*3+1] + x2*w[d*3+2];
}

// ---------------- per-channel BN stats over M rows -> a,b coeffs ----------------
__global__ __launch_bounds__(256) void colstats_kernel(const float* __restrict__ y,
                                                       int Mrows, int C,
                                                       const float* __restrict__ gamma,
                                                       const float* __restrict__ beta,
                                                       float* __restrict__ a_out,
                                                       float* __restrict__ b_out) {
    __shared__ float rs[256], rs2[256];
    int c = blockIdx.x;
    float s = 0.f, s2 = 0.f;
    for (int r = threadIdx.x; r < Mrows; r += 256) {
        float vv = y[r*C + c];
        s += vv; s2 += vv*vv;
    }
    rs[threadIdx.x] = s; rs2[threadIdx.x] = s2;
    __syncthreads();
    for (int off = 128; off > 0; off >>= 1) {
        if (threadIdx.x < off) {
            rs[threadIdx.x]  += rs[threadIdx.x+off];
            rs2[threadIdx.x] += rs2[threadIdx.x+off];
        }
        __syncthreads();
    }
    if (threadIdx.x == 0) {
        float mean = rs[0] / (float)Mrows;
        float var  = rs2[0] / (float)Mrows - mean*mean;
        float a = gamma[c] * rsqrtf(var + EPS);
        a_out[c] = a;
        b_out[c] = beta[c] - mean*a;
    }
}

// ---------------- encoder layer 2: y2 = relu(bn(y1)) @ W_e2^T (64 -> 64) ----------------
__global__ __launch_bounds__(256) void enc2_kernel(const float* __restrict__ y1,
                                                   const float* __restrict__ a,
                                                   const float* __restrict__ b,
                                                   const float* __restrict__ W,
                                                   float* __restrict__ y2) {
    __shared__ float wt[4096];
    __shared__ float f[256];
    for (int i = threadIdx.x; i < 4096; i += 256)
        wt[(i & 63)*64 + (i >> 6)] = W[i];
    int lin = blockIdx.x*256 + threadIdx.x;
    int c0 = threadIdx.x & 63;
    f[threadIdx.x] = fmaxf(a[c0]*y1[lin] + b[c0], 0.0f);
    __syncthreads();
    int rloc = threadIdx.x >> 6, d = threadIdx.x & 63;
    const float* fr = f + rloc*64;
    float acc = 0.f;
    #pragma unroll 8
    for (int c = 0; c < 64; ++c) acc += fr[c] * wt[c*64 + d];
    y2[lin] = acc;
}

// ---------------- u/v transform: u = f@Wl^T, v = f@(Wr-Wl)^T  (bf16 outputs) --------
template<int CIN, bool APPLY_BN>
__global__ __launch_bounds__(256) void uv_kernel(const float* __restrict__ fin,
                                                 const float* __restrict__ a,
                                                 const float* __restrict__ b,
                                                 const float* __restrict__ W,  // 128 x (2*CIN)
                                                 u16* __restrict__ u,
                                                 u16* __restrict__ v) {
    __shared__ float f[32*CIN];
    const int r0 = blockIdx.x * 32;
    for (int i = threadIdx.x; i < 32*CIN; i += 256) {
        float val = fin[r0*CIN + i];
        if (APPLY_BN) {
            int c = i & (CIN-1);
            val = fmaxf(a[c]*val + b[c], 0.0f);
        }
        f[i] = val;
    }
    __syncthreads();
    const int d  = threadIdx.x & 127;
    const int rg = threadIdx.x >> 7;   // 0..1
    float uacc[16], vacc[16];
    #pragma unroll
    for (int r = 0; r < 16; ++r) { uacc[r] = 0.f; vacc[r] = 0.f; }
    const float* wl = W + d*2*CIN;
    const float* wr = wl + CIN;
    for (int c = 0; c < CIN; ++c) {
        float wlv = wl[c];
        float wdv = wr[c] - wlv;
        #pragma unroll
        for (int r = 0; r < 16; ++r) {
            float xv = f[(rg*16 + r)*CIN + c];
            uacc[r] += xv*wlv;
            vacc[r] += xv*wdv;
        }
    }
    #pragma unroll
    for (int r = 0; r < 16; ++r) {
        int row = r0 + rg*16 + r;
        u[(size_t)row*128 + d] = (u16)f2bf(uacc[r]);
        v[(size_t)row*128 + d] = (u16)f2bf(vacc[r]);
    }
}

// ---------------- stats of e = u[idx] + v over all (b,n,k), per channel ----------------
// bf16 inputs, channel-major partial output pS[c][blk]
__global__ __launch_bounds__(256) void estats_kernel(const u16* __restrict__ u,
                                                     const u16* __restrict__ v,
                                                     const int* __restrict__ idx,
                                                     float* __restrict__ pS,
                                                     float* __restrict__ pS2) {
    __shared__ float red[4][132];
    const int t = threadIdx.x;
    const int l = t & 63;
    const int g = t >> 6;
    const int c2 = l*2;
    const int row0 = blockIdx.x * 256;
    float s0=0.f, s1=0.f, q0=0.f, q1=0.f;
    for (int r = 0; r < 64; ++r) {
        int row = row0 + r*4 + g;
        int n = row >> 5;
        int j = idx[row];
        u32 uw = *(const u32*)&u[(size_t)j*128 + c2];
        u32 vw = *(const u32*)&v[(size_t)n*128 + c2];
        float e0 = __uint_as_float(uw << 16)        + __uint_as_float(vw << 16);
        float e1 = __uint_as_float(uw & 0xffff0000u) + __uint_as_float(vw & 0xffff0000u);
        s0 += e0; q0 += e0*e0;
        s1 += e1; q1 += e1*e1;
    }
    red[g][c2] = s0; red[g][c2+1] = s1;
    __syncthreads();
    if (t < 128) pS[t*NBLK + blockIdx.x] = red[0][t]+red[1][t]+red[2][t]+red[3][t];
    __syncthreads();
    red[g][c2] = q0; red[g][c2+1] = q1;
    __syncthreads();
    if (t < 128) pS2[t*NBLK + blockIdx.x] = red[0][t]+red[1][t]+red[2][t]+red[3][t];
}

// ---------------- finalize BN coeffs: 128 blocks, coalesced channel-major reads -----
__global__ __launch_bounds__(256) void reduce_ab_kernel(const float* __restrict__ pS,
                                                        const float* __restrict__ pS2,
                                                        int nblk, float count,
                                                        const float* __restrict__ gamma,
                                                        const float* __restrict__ beta,
                                                        float* __restrict__ a_out,
                                                        float* __restrict__ b_out) {
    __shared__ double rs[256], rs2[256];
    const int c = blockIdx.x;
    const int t = threadIdx.x;
    double s = 0.0, s2 = 0.0;
    for (int i = t; i < nblk; i += 256) {
        s  += (double)pS [c*NBLK + i];
        s2 += (double)pS2[c*NBLK + i];
    }
    rs[t] = s; rs2[t] = s2;
    __syncthreads();
    for (int off = 128; off > 0; off >>= 1) {
        if (t < off) { rs[t] += rs[t+off]; rs2[t] += rs2[t+off]; }
        __syncthreads();
    }
    if (t == 0) {
        double mean = rs[0] / (double)count;
        double var  = rs2[0] / (double)count - mean*mean;
        float a = gamma[c] * (float)(1.0 / sqrt(var + (double)EPS));
        a_out[c] = a;
        b_out[c] = beta[c] - (float)mean * a;
    }
}

// ---------------- local_op core via MFMA bf16 ----------------
// staging: act[r,c] = relu(a1[c]*(u[idx[p,r],c]+v[p,c]) + b1[c]) -> bf16 LDS
// h2 = act @ W2^T via mfma_f32_16x16x32_bf16.
// STATS: per-channel sum/sumsq of h2 -> pS/pS2 (channel-major).
// OUT:   out[p,d] = relu(a2[d]*max_r(h2[r,d]) + b2[d])   (a2>0)
__device__ inline u32 bnrelu_pack(u32 uw, u32 vw, float a0, float b0, float a1, float b1) {
    float e0 = __uint_as_float(uw << 16)         + __uint_as_float(vw << 16);
    float e1 = __uint_as_float(uw & 0xffff0000u) + __uint_as_float(vw & 0xffff0000u);
    float h0 = fmaxf(a0*e0 + b0, 0.f);
    float h1 = fmaxf(a1*e1 + b1, 0.f);
    return ((u32)(u16)f2bf(h1) << 16) | (u16)f2bf(h0);
}

template<bool STATS>
__global__ __launch_bounds__(256, 3) void local_mfma_kernel(
        const u16* __restrict__ u, const u16* __restrict__ v,
        const int* __restrict__ idx,
        const float* __restrict__ a1, const float* __restrict__ b1,
        const float* __restrict__ W2,          // 128x128 row-major [d][c]
        const float* __restrict__ a2, const float* __restrict__ b2,
        float* __restrict__ pS, float* __restrict__ pS2,
        float* __restrict__ outp) {
    __shared__ short wlds[128*136];     // bf16 W2 [d][c], pad 136
    __shared__ short alds[2][32*136];   // bf16 act [r][c], double-buffered
    const int t  = threadIdx.x;
    const int l  = t & 63;
    const int w  = t >> 6;       // wave 0..3 -> output cols 32w..32w+31
    const int lr = l & 15;
    const int kg = l >> 4;       // 0..3

    for (int i = t*4; i < 16384; i += 1024) {
        float4 wv = *(const float4*)&W2[i];
        int d = i >> 7, c = i & 127;
        short4v pk;
        pk.x = f2bf(wv.x); pk.y = f2bf(wv.y); pk.z = f2bf(wv.z); pk.w = f2bf(wv.w);
        *(short4v*)&wlds[d*136 + c] = pk;
    }

    const int sr = t >> 3;          // staging row 0..31
    const int sc = (t & 7) * 16;    // staging col base (16 channels)

    float a1v[16], b1v[16];
    #pragma unroll
    for (int i = 0; i < 16; ++i) { a1v[i] = a1[sc + i]; b1v[i] = b1[sc + i]; }

    float a2v[2], b2v[2];
    if (!STATS) {
        #pragma unroll
        for (int ct = 0; ct < 2; ++ct) {
            int d = w*32 + ct*16 + lr;
            a2v[ct] = a2[d]; b2v[ct] = b2[d];
        }
    }
    float sacc[2] = {0.f, 0.f}, s2acc[2] = {0.f, 0.f};

    const int p0 = blockIdx.x * 8;

    auto stage = [&](int p, int bi) {
        int j = idx[p*KK + sr];
        const u32* up = (const u32*)(u + (size_t)j*128 + sc);
        const u32* vp = (const u32*)(v + (size_t)p*128 + sc);
        uint4 ua = *(const uint4*)up;
        uint4 ub = *(const uint4*)(up + 4);
        uint4 va = *(const uint4*)vp;
        uint4 vb = *(const uint4*)(vp + 4);
        uint4 w0, w1;
        w0.x = bnrelu_pack(ua.x, va.x, a1v[0],  b1v[0],  a1v[1],  b1v[1]);
        w0.y = bnrelu_pack(ua.y, va.y, a1v[2],  b1v[2],  a1v[3],  b1v[3]);
        w0.z = bnrelu_pack(ua.z, va.z, a1v[4],  b1v[4],  a1v[5],  b1v[5]);
        w0.w = bnrelu_pack(ua.w, va.w, a1v[6],  b1v[6],  a1v[7],  b1v[7]);
        w1.x = bnrelu_pack(ub.x, vb.x, a1v[8],  b1v[8],  a1v[9],  b1v[9]);
        w1.y = bnrelu_pack(ub.y, vb.y, a1v[10], b1v[10], a1v[11], b1v[11]);
        w1.z = bnrelu_pack(ub.z, vb.z, a1v[12], b1v[12], a1v[13], b1v[13]);
        w1.w = bnrelu_pack(ub.w, vb.w, a1v[14], b1v[14], a1v[15], b1v[15]);
        *(uint4*)(void*)&alds[bi][sr*136 + sc]     = w0;
        *(uint4*)(void*)&alds[bi][sr*136 + sc + 8] = w1;
    };

    stage(p0, 0);
    __syncthreads();

    for (int g = 0; g < 8; ++g) {
        const int p = p0 + g;
        if (g < 7) stage(p + 1, (g + 1) & 1);
        const short* ab = alds[g & 1];
        f32x4 acc[2][2];
        #pragma unroll
        for (int rt = 0; rt < 2; ++rt)
            #pragma unroll
            for (int ct = 0; ct < 2; ++ct)
                acc[rt][ct] = (f32x4){0.f, 0.f, 0.f, 0.f};
        #pragma unroll
        for (int kk = 0; kk < 4; ++kk) {
            const int ko = kk*32 + kg*8;
            short8v a0 = *(const short8v*)&ab[lr*136 + ko];
            short8v a1f = *(const short8v*)&ab[(16 + lr)*136 + ko];
            short8v b0 = *(const short8v*)&wlds[(w*32 + lr)*136 + ko];
            short8v b1f = *(const short8v*)&wlds[(w*32 + 16 + lr)*136 + ko];
            acc[0][0] = __builtin_amdgcn_mfma_f32_16x16x32_bf16(a0,  b0,  acc[0][0], 0, 0, 0);
            acc[1][0] = __builtin_amdgcn_mfma_f32_16x16x32_bf16(a1f, b0,  acc[1][0], 0, 0, 0);
            acc[0][1] = __builtin_amdgcn_mfma_f32_16x16x32_bf16(a0,  b1f, acc[0][1], 0, 0, 0);
            acc[1][1] = __builtin_amdgcn_mfma_f32_16x16x32_bf16(a1f, b1f, acc[1][1], 0, 0, 0);
        }
        if (STATS) {
            #pragma unroll
            for (int ct = 0; ct < 2; ++ct) {
                float s = 0.f, q = 0.f;
                #pragma unroll
                for (int rt = 0; rt < 2; ++rt)
                    #pragma unroll
                    for (int e = 0; e < 4; ++e) {
                        float h = acc[rt][ct][e];
                        s += h; q += h*h;
                    }
                sacc[ct] += s; s2acc[ct] += q;
            }
        } else {
            #pragma unroll
            for (int ct = 0; ct < 2; ++ct) {
                float m = acc[0][ct][0];
                #pragma unroll
                for (int rt = 0; rt < 2; ++rt)
                    #pragma unroll
                    for (int e = 0; e < 4; ++e)
                        m = fmaxf(m, acc[rt][ct][e]);
                m = fmaxf(m, __shfl_xor(m, 16, 64));
                m = fmaxf(m, __shfl_xor(m, 32, 64));
                if (l < 16) {
                    float val = fmaxf(a2v[ct]*m + b2v[ct], 0.f);
                    outp[(size_t)p*128 + w*32 + ct*16 + lr] = val;
                }
            }
        }
        __syncthreads();
    }
    if (STATS) {
        #pragma unroll
        for (int ct = 0; ct < 2; ++ct) {
            float s = sacc[ct], q = s2acc[ct];
            s += __shfl_xor(s, 16, 64); s += __shfl_xor(s, 32, 64);
            q += __shfl_xor(q, 16, 64); q += __shfl_xor(q, 32, 64);
            if (l < 16) {
                pS [(w*32 + ct*16 + lr)*NBLK + blockIdx.x] = s;
                pS2[(w*32 + ct*16 + lr)*NBLK + blockIdx.x] = q;
            }
        }
    }
}

// ---------------- host launcher ----------------
extern "C" void kernel_launch(void* const* d_in, const int* in_sizes, int n_in,
                              void* d_out, int out_size, void* d_ws, size_t ws_size,
                              hipStream_t stream) {
    const float* x     = (const float*)d_in[0];
    const float* W_e1  = (const float*)d_in[1];
    const float* g_e1  = (const float*)d_in[2];
    const float* b_e1  = (const float*)d_in[3];
    const float* W_e2  = (const float*)d_in[4];
    const float* g_e2  = (const float*)d_in[5];
    const float* b_e2  = (const float*)d_in[6];
    const float* W_l1a = (const float*)d_in[7];
    const float* g_l1a = (const float*)d_in[8];
    const float* b_l1a = (const float*)d_in[9];
    const float* W_l1b = (const float*)d_in[10];
    const float* g_l1b = (const float*)d_in[11];
    const float* b_l1b = (const float*)d_in[12];
    const float* W_l2a = (const float*)d_in[13];
    const float* g_l2a = (const float*)d_in[14];
    const float* b_l2a = (const float*)d_in[15];
    const float* W_l2b = (const float*)d_in[16];
    const float* g_l2b = (const float*)d_in[17];
    const float* b_l2b = (const float*)d_in[18];

    float* ws   = (float*)d_ws;
    int*   idx  = (int*)(ws + OFF_IDX);
    float* y1   = ws + OFF_Y1;
    float* y2   = ws + OFF_Y2;
    u16*   u    = (u16*)(ws + OFF_U);
    u16*   v    = (u16*)(ws + OFF_V);
    float* f2   = ws + OFF_F2;
    float* pS   = ws + OFF_PS;
    float* pS2  = ws + OFF_PS2;
    float* ab   = ws + OFF_AB;
    float *a_e1 = ab,        *be1 = ab + 128,
          *a_e2 = ab + 256,  *be2 = ab + 384,
          *a_1a = ab + 512,  *b_1a = ab + 640,
          *a_1b = ab + 768,  *b_1b = ab + 896,
          *a_2a = ab + 1024, *b_2a = ab + 1152,
          *a_2b = ab + 1280, *b_2b = ab + 1408;

    knn_kernel<<<dim3(MM/4), dim3(256), 0, stream>>>(x, idx);

    enc1_kernel<<<dim3(MM*64/256), dim3(256), 0, stream>>>(x, W_e1, y1);
    colstats_kernel<<<dim3(64), dim3(256), 0, stream>>>(y1, MM, 64, g_e1, b_e1, a_e1, be1);
    enc2_kernel<<<dim3(MM*64/256), dim3(256), 0, stream>>>(y1, a_e1, be1, W_e2, y2);
    colstats_kernel<<<dim3(64), dim3(256), 0, stream>>>(y2, MM, 64, g_e2, b_e2, a_e2, be2);

    // ---- local_op 1 ----
    uv_kernel<64, true><<<dim3(MM/32), dim3(256), 0, stream>>>(y2, a_e2, be2, W_l1a, u, v);
    estats_kernel<<<dim3(LL/256), dim3(256), 0, stream>>>(u, v, idx, pS, pS2);
    reduce_ab_kernel<<<dim3(128), dim3(256), 0, stream>>>(pS, pS2, LL/256, (float)LL, g_l1a, b_l1a, a_1a, b_1a);
    local_mfma_kernel<true><<<dim3(MM/8), dim3(256), 0, stream>>>(u, v, idx, a_1a, b_1a, W_l1b,
                                                                  nullptr, nullptr, pS, pS2, nullptr);
    reduce_ab_kernel<<<dim3(128), dim3(256), 0, stream>>>(pS, pS2, MM/8, (float)LL, g_l1b, b_l1b, a_1b, b_1b);
    local_mfma_kernel<false><<<dim3(MM/8), dim3(256), 0, stream>>>(u, v, idx, a_1a, b_1a, W_l1b,
                                                                   a_1b, b_1b, nullptr, nullptr, f2);

    // ---- local_op 2 ----
    uv_kernel<128, false><<<dim3(MM/32), dim3(256), 0, stream>>>(f2, nullptr, nullptr, W_l2a, u, v);
    estats_kernel<<<dim3(LL/256), dim3(256), 0, stream>>>(u, v, idx, pS, pS2);
    reduce_ab_kernel<<<dim3(128), dim3(256), 0, stream>>>(pS, pS2, LL/256, (float)LL, g_l2a, b_l2a, a_2a, b_2a);
    local_mfma_kernel<true><<<dim3(MM/8), dim3(256), 0, stream>>>(u, v, idx, a_2a, b_2a, W_l2b,
                                                                  nullptr, nullptr, pS, pS2, nullptr);
    reduce_ab_kernel<<<dim3(128), dim3(256), 0, stream>>>(pS, pS2, MM/8, (float)LL, g_l2b, b_l2b, a_2b, b_2b);
    local_mfma_kernel<false><<<dim3(MM/8), dim3(256), 0, stream>>>(u, v, idx, a_2a, b_2a, W_l2b,
                                                                   a_2b, b_2b, nullptr, nullptr, (float*)d_out);
}

// Round 6
// 526.293 us; speedup vs baseline: 7.8776x; 1.0999x over previous
//
#include <hip/hip_runtime.h>
#include <stdint.h>
#include <math.h>

#define BB 8
#define NN 2048
#define KK 32
#define MM (BB*NN)      // 16384 points total
#define LL (MM*KK)      // 524288 gathered rows
#define NBLK 2048       // partial-stat blocks (estats grid == local grid == 2048)
static constexpr float EPS = 1e-5f;

typedef short  short4v __attribute__((ext_vector_type(4)));
typedef short  short8v __attribute__((ext_vector_type(8)));
typedef float  f32x4   __attribute__((ext_vector_type(4)));
typedef unsigned int u32;
typedef unsigned short u16;

__device__ inline short f2bf(float f) {   // RNE float->bf16
    unsigned u = __float_as_uint(f);
    u += 0x7fffu + ((u >> 16) & 1u);
    return (short)(u >> 16);
}

// wave64 u32 min-reduce via DPP (row_shr 1/2/4/8, row_bcast 15/31), result
// broadcast to all lanes through readlane(63). ~12 VALU ops, no LDS traffic.
__device__ inline u32 dpp_min_bcast_u32(u32 v) {
    u32 t;
    t = (u32)__builtin_amdgcn_update_dpp((int)v, (int)v, 0x111, 0xf, 0xf, false); v = t < v ? t : v;
    t = (u32)__builtin_amdgcn_update_dpp((int)v, (int)v, 0x112, 0xf, 0xf, false); v = t < v ? t : v;
    t = (u32)__builtin_amdgcn_update_dpp((int)v, (int)v, 0x114, 0xf, 0xf, false); v = t < v ? t : v;
    t = (u32)__builtin_amdgcn_update_dpp((int)v, (int)v, 0x118, 0xf, 0xf, false); v = t < v ? t : v;
    t = (u32)__builtin_amdgcn_update_dpp((int)v, (int)v, 0x142, 0xf, 0xf, false); v = t < v ? t : v;
    t = (u32)__builtin_amdgcn_update_dpp((int)v, (int)v, 0x143, 0xf, 0xf, false); v = t < v ? t : v;
    return (u32)__builtin_amdgcn_readlane((int)v, 63);
}

// ---------------- workspace layout (float offsets; u/v regions half-used as bf16) ----
#define OFF_IDX   0                        // int[LL]
#define OFF_Y1    (LL)                     // float[MM*64]
#define OFF_Y2    (OFF_Y1 + MM*64)         // float[MM*64]
#define OFF_U     (OFF_Y2 + MM*64)         // u16[MM*128] (in float[MM*128] region)
#define OFF_V     (OFF_U + MM*128)         // u16[MM*128]
#define OFF_F2    (OFF_V + MM*128)         // float[MM*128]
#define OFF_PS    (OFF_F2 + MM*128)        // float[128*NBLK] channel-major
#define OFF_PS2   (OFF_PS + 2048*128)      // float[128*NBLK]
#define OFF_AB    (OFF_PS2 + 2048*128)     // float[1536]

// ---------------- kNN: wave-per-query, DPP-reduce top-32 extraction ----------------
// Lane owns candidates j = s*64+lane; dist bits in a private read-only LDS row
// (written once at setup) and running per-lane min (dist,j) in registers.
// Removal tracked by a per-lane 32-bit mask (fetched cross-lane via readlane).
// 32 iterations: DPP-min(dist) + DPP-min(j | dist==min) -> winner; collective
// reread of winner lane's 32 slots + 2 DPP-mins rebuilds that lane's min.
// Key order (dist, j) ascending == jax.lax.top_k(-d) with stable ties.
__global__ __launch_bounds__(256) void knn_kernel(const float* __restrict__ x,
                                                  int* __restrict__ idx_out) {
    __shared__ u32 dlds[4][64][33];   // 33.8 KB -> 4 blocks/CU; read-only after setup
    const int t    = threadIdx.x;
    const int lane = t & 63;
    const int wv   = t >> 6;
    const int q    = blockIdx.x * 4 + wv;
    const int b    = q >> 11;
    const int n    = q & (NN - 1);

    const float* xb = x + (size_t)b * NN * 3;
    const float qx = xb[n*3], qy = xb[n*3+1], qz = xb[n*3+2];
    const float sqn = qx*qx + qy*qy + qz*qz;

    u32 mind = 0xFFFFFFFFu;   // per-lane running min dist bits
    u32 minj = 0xFFFFFFFFu;   // its candidate index j
    #pragma unroll 4
    for (int s = 0; s < 32; ++s) {
        int j = s*64 + lane;
        const float* pj = xb + j*3;
        float x0 = pj[0], x1 = pj[1], x2 = pj[2];
        float sqj = x0*x0 + x1*x1 + x2*x2;
        float dot = qx*x0 + qy*x1 + qz*x2;
        float d = sqn + sqj - 2.0f*dot;
        d = (j == n) ? 0.0f : fmaxf(d, 0.0f);
        u32 db = __float_as_uint(d);
        dlds[wv][lane][s] = db;
        if (db < mind) { mind = db; minj = (u32)j; }   // s ascending => smallest j on ties
    }

    u32 removed = 0;
    const int out_base = q * KK;
    const int gbase    = b * NN;
    const int rl = lane & 31;
    #pragma unroll 1
    for (int it = 0; it < KK; ++it) {
        // winner: smallest (dist, j) over lane mins
        u32 gmin = dpp_min_bcast_u32(mind);
        u32 jc   = (mind == gmin) ? minj : 0xFFFFFFFFu;
        u32 gj   = dpp_min_bcast_u32(jc);
        if (lane == 0) idx_out[out_base + it] = gbase + (int)gj;
        const int wl = (int)(gj & 63u);
        const int sw = (int)(gj >> 6);
        if (lane == wl) removed |= (1u << sw);
        // rebuild lane wl's min: collective reread of its 32 slots
        u32 wmask = (u32)__builtin_amdgcn_readlane((int)removed, wl);
        u32 db = dlds[wv][wl][rl];
        if ((wmask >> rl) & 1u) db = 0xFFFFFFFFu;
        u32 nmind = dpp_min_bcast_u32(db);
        u32 sc    = (db == nmind) ? (u32)rl : 0xFFFFFFFFu;
        u32 nsl   = dpp_min_bcast_u32(sc);
        if (lane == wl) { mind = nmind; minj = nsl*64u + (u32)wl; }
    }
}

// ---------------- encoder layer 1: y1 = x @ W_e1^T  (3 -> 64) ----------------
__global__ __launch_bounds__(256) void enc1_kernel(const float* __restrict__ x,
                                                   const float* __restrict__ W,
                                                   float* __restrict__ y1) {
    __shared__ float w[192];
    if (threadIdx.x < 192) w[threadIdx.x] = W[threadIdx.x];
    __syncthreads();
    int lin = blockIdx.x*256 + threadIdx.x;
    int row = lin >> 6, d = lin & 63;
    float x0 = x[row*3], x1 = x[row*3+1], x2 = x[row*3+2];
    y1[lin] = x0*w[d*3] + x1*w[d*3+1] + x2*w[d*3+2];
}

// ---------------- per-channel BN stats over M rows -> a,b coeffs ----------------
__global__ __launch_bounds__(256) void colstats_kernel(const float* __restrict__ y,
                                                       int Mrows, int C,
                                                       const float* __restrict__ gamma,
                                                       const float* __restrict__ beta,
                                                       float* __restrict__ a_out,
                                                       float* __restrict__ b_out) {
    __shared__ float rs[256], rs2[256];
    int c = blockIdx.x;
    float s = 0.f, s2 = 0.f;
    for (int r = threadIdx.x; r < Mrows; r += 256) {
        float vv = y[r*C + c];
        s += vv; s2 += vv*vv;
    }
    rs[threadIdx.x] = s; rs2[threadIdx.x] = s2;
    __syncthreads();
    for (int off = 128; off > 0; off >>= 1) {
        if (threadIdx.x < off) {
            rs[threadIdx.x]  += rs[threadIdx.x+off];
            rs2[threadIdx.x] += rs2[threadIdx.x+off];
        }
        __syncthreads();
    }
    if (threadIdx.x == 0) {
        float mean = rs[0] / (float)Mrows;
        float var  = rs2[0] / (float)Mrows - mean*mean;
        float a = gamma[c] * rsqrtf(var + EPS);
        a_out[c] = a;
        b_out[c] = beta[c] - mean*a;
    }
}

// ---------------- encoder layer 2: y2 = relu(bn(y1)) @ W_e2^T (64 -> 64) ----------------
__global__ __launch_bounds__(256) void enc2_kernel(const float* __restrict__ y1,
                                                   const float* __restrict__ a,
                                                   const float* __restrict__ b,
                                                   const float* __restrict__ W,
                                                   float* __restrict__ y2) {
    __shared__ float wt[4096];
    __shared__ float f[256];
    for (int i = threadIdx.x; i < 4096; i += 256)
        wt[(i & 63)*64 + (i >> 6)] = W[i];
    int lin = blockIdx.x*256 + threadIdx.x;
    int c0 = threadIdx.x & 63;
    f[threadIdx.x] = fmaxf(a[c0]*y1[lin] + b[c0], 0.0f);
    __syncthreads();
    int rloc = threadIdx.x >> 6, d = threadIdx.x & 63;
    const float* fr = f + rloc*64;
    float acc = 0.f;
    #pragma unroll 8
    for (int c = 0; c < 64; ++c) acc += fr[c] * wt[c*64 + d];
    y2[lin] = acc;
}

// ---------------- u/v transform: u = f@Wl^T, v = f@(Wr-Wl)^T  (bf16 outputs) --------
template<int CIN, bool APPLY_BN>
__global__ __launch_bounds__(256) void uv_kernel(const float* __restrict__ fin,
                                                 const float* __restrict__ a,
                                                 const float* __restrict__ b,
                                                 const float* __restrict__ W,  // 128 x (2*CIN)
                                                 u16* __restrict__ u,
                                                 u16* __restrict__ v) {
    __shared__ float f[32*CIN];
    const int r0 = blockIdx.x * 32;
    for (int i = threadIdx.x; i < 32*CIN; i += 256) {
        float val = fin[r0*CIN + i];
        if (APPLY_BN) {
            int c = i & (CIN-1);
            val = fmaxf(a[c]*val + b[c], 0.0f);
        }
        f[i] = val;
    }
    __syncthreads();
    const int d  = threadIdx.x & 127;
    const int rg = threadIdx.x >> 7;   // 0..1
    float uacc[16], vacc[16];
    #pragma unroll
    for (int r = 0; r < 16; ++r) { uacc[r] = 0.f; vacc[r] = 0.f; }
    const float* wl = W + d*2*CIN;
    const float* wr = wl + CIN;
    for (int c = 0; c < CIN; ++c) {
        float wlv = wl[c];
        float wdv = wr[c] - wlv;
        #pragma unroll
        for (int r = 0; r < 16; ++r) {
            float xv = f[(rg*16 + r)*CIN + c];
            uacc[r] += xv*wlv;
            vacc[r] += xv*wdv;
        }
    }
    #pragma unroll
    for (int r = 0; r < 16; ++r) {
        int row = r0 + rg*16 + r;
        u[(size_t)row*128 + d] = (u16)f2bf(uacc[r]);
        v[(size_t)row*128 + d] = (u16)f2bf(vacc[r]);
    }
}

// ---------------- stats of e = u[idx] + v over all (b,n,k), per channel ----------------
// bf16 inputs, channel-major partial output pS[c][blk]
__global__ __launch_bounds__(256) void estats_kernel(const u16* __restrict__ u,
                                                     const u16* __restrict__ v,
                                                     const int* __restrict__ idx,
                                                     float* __restrict__ pS,
                                                     float* __restrict__ pS2) {
    __shared__ float red[4][132];
    const int t = threadIdx.x;
    const int l = t & 63;
    const int g = t >> 6;
    const int c2 = l*2;
    const int row0 = blockIdx.x * 256;
    float s0=0.f, s1=0.f, q0=0.f, q1=0.f;
    for (int r = 0; r < 64; ++r) {
        int row = row0 + r*4 + g;
        int n = row >> 5;
        int j = idx[row];
        u32 uw = *(const u32*)&u[(size_t)j*128 + c2];
        u32 vw = *(const u32*)&v[(size_t)n*128 + c2];
        float e0 = __uint_as_float(uw << 16)        + __uint_as_float(vw << 16);
        float e1 = __uint_as_float(uw & 0xffff0000u) + __uint_as_float(vw & 0xffff0000u);
        s0 += e0; q0 += e0*e0;
        s1 += e1; q1 += e1*e1;
    }
    red[g][c2] = s0; red[g][c2+1] = s1;
    __syncthreads();
    if (t < 128) pS[t*NBLK + blockIdx.x] = red[0][t]+red[1][t]+red[2][t]+red[3][t];
    __syncthreads();
    red[g][c2] = q0; red[g][c2+1] = q1;
    __syncthreads();
    if (t < 128) pS2[t*NBLK + blockIdx.x] = red[0][t]+red[1][t]+red[2][t]+red[3][t];
}

// ---------------- finalize BN coeffs: 128 blocks, coalesced channel-major reads -----
__global__ __launch_bounds__(256) void reduce_ab_kernel(const float* __restrict__ pS,
                                                        const float* __restrict__ pS2,
                                                        int nblk, float count,
                                                        const float* __restrict__ gamma,
                                                        const float* __restrict__ beta,
                                                        float* __restrict__ a_out,
                                                        float* __restrict__ b_out) {
    __shared__ double rs[256], rs2[256];
    const int c = blockIdx.x;
    const int t = threadIdx.x;
    double s = 0.0, s2 = 0.0;
    for (int i = t; i < nblk; i += 256) {
        s  += (double)pS [c*NBLK + i];
        s2 += (double)pS2[c*NBLK + i];
    }
    rs[t] = s; rs2[t] = s2;
    __syncthreads();
    for (int off = 128; off > 0; off >>= 1) {
        if (t < off) { rs[t] += rs[t+off]; rs2[t] += rs2[t+off]; }
        __syncthreads();
    }
    if (t == 0) {
        double mean = rs[0] / (double)count;
        double var  = rs2[0] / (double)count - mean*mean;
        float a = gamma[c] * (float)(1.0 / sqrt(var + (double)EPS));
        a_out[c] = a;
        b_out[c] = beta[c] - (float)mean * a;
    }
}

// ---------------- local_op core via MFMA bf16 ----------------
// staging: act[r,c] = relu(a1[c]*(u[idx[p,r],c]+v[p,c]) + b1[c]) -> bf16 LDS
// h2 = act @ W2^T via mfma_f32_16x16x32_bf16.
// STATS: per-channel sum/sumsq of h2 -> pS/pS2 (channel-major).
// OUT:   out[p,d] = relu(a2[d]*max_r(h2[r,d]) + b2[d])   (a2>0)
__device__ inline u32 bnrelu_pack(u32 uw, u32 vw, float a0, float b0, float a1, float b1) {
    float e0 = __uint_as_float(uw << 16)         + __uint_as_float(vw << 16);
    float e1 = __uint_as_float(uw & 0xffff0000u) + __uint_as_float(vw & 0xffff0000u);
    float h0 = fmaxf(a0*e0 + b0, 0.f);
    float h1 = fmaxf(a1*e1 + b1, 0.f);
    return ((u32)(u16)f2bf(h1) << 16) | (u16)f2bf(h0);
}

template<bool STATS>
__global__ __launch_bounds__(256, 3) void local_mfma_kernel(
        const u16* __restrict__ u, const u16* __restrict__ v,
        const int* __restrict__ idx,
        const float* __restrict__ a1, const float* __restrict__ b1,
        const float* __restrict__ W2,          // 128x128 row-major [d][c]
        const float* __restrict__ a2, const float* __restrict__ b2,
        float* __restrict__ pS, float* __restrict__ pS2,
        float* __restrict__ outp) {
    __shared__ short wlds[128*136];     // bf16 W2 [d][c], pad 136
    __shared__ short alds[2][32*136];   // bf16 act [r][c], double-buffered
    const int t  = threadIdx.x;
    const int l  = t & 63;
    const int w  = t >> 6;       // wave 0..3 -> output cols 32w..32w+31
    const int lr = l & 15;
    const int kg = l >> 4;       // 0..3

    for (int i = t*4; i < 16384; i += 1024) {
        float4 wv = *(const float4*)&W2[i];
        int d = i >> 7, c = i & 127;
        short4v pk;
        pk.x = f2bf(wv.x); pk.y = f2bf(wv.y); pk.z = f2bf(wv.z); pk.w = f2bf(wv.w);
        *(short4v*)&wlds[d*136 + c] = pk;
    }

    const int sr = t >> 3;          // staging row 0..31
    const int sc = (t & 7) * 16;    // staging col base (16 channels)

    float a1v[16], b1v[16];
    #pragma unroll
    for (int i = 0; i < 16; ++i) { a1v[i] = a1[sc + i]; b1v[i] = b1[sc + i]; }

    float a2v[2], b2v[2];
    if (!STATS) {
        #pragma unroll
        for (int ct = 0; ct < 2; ++ct) {
            int d = w*32 + ct*16 + lr;
            a2v[ct] = a2[d]; b2v[ct] = b2[d];
        }
    }
    float sacc[2] = {0.f, 0.f}, s2acc[2] = {0.f, 0.f};

    const int p0 = blockIdx.x * 8;

    auto stage = [&](int p, int bi) {
        int j = idx[p*KK + sr];
        const u32* up = (const u32*)(u + (size_t)j*128 + sc);
        const u32* vp = (const u32*)(v + (size_t)p*128 + sc);
        uint4 ua = *(const uint4*)up;
        uint4 ub = *(const uint4*)(up + 4);
        uint4 va = *(const uint4*)vp;
        uint4 vb = *(const uint4*)(vp + 4);
        uint4 w0, w1;
        w0.x = bnrelu_pack(ua.x, va.x, a1v[0],  b1v[0],  a1v[1],  b1v[1]);
        w0.y = bnrelu_pack(ua.y, va.y, a1v[2],  b1v[2],  a1v[3],  b1v[3]);
        w0.z = bnrelu_pack(ua.z, va.z, a1v[4],  b1v[4],  a1v[5],  b1v[5]);
        w0.w = bnrelu_pack(ua.w, va.w, a1v[6],  b1v[6],  a1v[7],  b1v[7]);
        w1.x = bnrelu_pack(ub.x, vb.x, a1v[8],  b1v[8],  a1v[9],  b1v[9]);
        w1.y = bnrelu_pack(ub.y, vb.y, a1v[10], b1v[10], a1v[11], b1v[11]);
        w1.z = bnrelu_pack(ub.z, vb.z, a1v[12], b1v[12], a1v[13], b1v[13]);
        w1.w = bnrelu_pack(ub.w, vb.w, a1v[14], b1v[14], a1v[15], b1v[15]);
        *(uint4*)(void*)&alds[bi][sr*136 + sc]     = w0;
        *(uint4*)(void*)&alds[bi][sr*136 + sc + 8] = w1;
    };

    stage(p0, 0);
    __syncthreads();

    for (int g = 0; g < 8; ++g) {
        const int p = p0 + g;
        if (g < 7) stage(p + 1, (g + 1) & 1);
        const short* ab = alds[g & 1];
        f32x4 acc[2][2];
        #pragma unroll
        for (int rt = 0; rt < 2; ++rt)
            #pragma unroll
            for (int ct = 0; ct < 2; ++ct)
                acc[rt][ct] = (f32x4){0.f, 0.f, 0.f, 0.f};
        #pragma unroll
        for (int kk = 0; kk < 4; ++kk) {
            const int ko = kk*32 + kg*8;
            short8v a0 = *(const short8v*)&ab[lr*136 + ko];
            short8v a1f = *(const short8v*)&ab[(16 + lr)*136 + ko];
            short8v b0 = *(const short8v*)&wlds[(w*32 + lr)*136 + ko];
            short8v b1f = *(const short8v*)&wlds[(w*32 + 16 + lr)*136 + ko];
            acc[0][0] = __builtin_amdgcn_mfma_f32_16x16x32_bf16(a0,  b0,  acc[0][0], 0, 0, 0);
            acc[1][0] = __builtin_amdgcn_mfma_f32_16x16x32_bf16(a1f, b0,  acc[1][0], 0, 0, 0);
            acc[0][1] = __builtin_amdgcn_mfma_f32_16x16x32_bf16(a0,  b1f, acc[0][1], 0, 0, 0);
            acc[1][1] = __builtin_amdgcn_mfma_f32_16x16x32_bf16(a1f, b1f, acc[1][1], 0, 0, 0);
        }
        if (STATS) {
            #pragma unroll
            for (int ct = 0; ct < 2; ++ct) {
                float s = 0.f, q = 0.f;
                #pragma unroll
                for (int rt = 0; rt < 2; ++rt)
                    #pragma unroll
                    for (int e = 0; e < 4; ++e) {
                        float h = acc[rt][ct][e];
                        s += h; q += h*h;
                    }
                sacc[ct] += s; s2acc[ct] += q;
            }
        } else {
            #pragma unroll
            for (int ct = 0; ct < 2; ++ct) {
                float m = acc[0][ct][0];
                #pragma unroll
                for (int rt = 0; rt < 2; ++rt)
                    #pragma unroll
                    for (int e = 0; e < 4; ++e)
                        m = fmaxf(m, acc[rt][ct][e]);
                m = fmaxf(m, __shfl_xor(m, 16, 64));
                m = fmaxf(m, __shfl_xor(m, 32, 64));
                if (l < 16) {
                    float val = fmaxf(a2v[ct]*m + b2v[ct], 0.f);
                    outp[(size_t)p*128 + w*32 + ct*16 + lr] = val;
                }
            }
        }
        __syncthreads();
    }
    if (STATS) {
        #pragma unroll
        for (int ct = 0; ct < 2; ++ct) {
            float s = sacc[ct], q = s2acc[ct];
            s += __shfl_xor(s, 16, 64); s += __shfl_xor(s, 32, 64);
            q += __shfl_xor(q, 16, 64); q += __shfl_xor(q, 32, 64);
            if (l < 16) {
                pS [(w*32 + ct*16 + lr)*NBLK + blockIdx.x] = s;
                pS2[(w*32 + ct*16 + lr)*NBLK + blockIdx.x] = q;
            }
        }
    }
}

// ---------------- host launcher ----------------
extern "C" void kernel_launch(void* const* d_in, const int* in_sizes, int n_in,
                              void* d_out, int out_size, void* d_ws, size_t ws_size,
                              hipStream_t stream) {
    const float* x     = (const float*)d_in[0];
    const float* W_e1  = (const float*)d_in[1];
    const float* g_e1  = (const float*)d_in[2];
    const float* b_e1  = (const float*)d_in[3];
    const float* W_e2  = (const float*)d_in[4];
    const float* g_e2  = (const float*)d_in[5];
    const float* b_e2  = (const float*)d_in[6];
    const float* W_l1a = (const float*)d_in[7];
    const float* g_l1a = (const float*)d_in[8];
    const float* b_l1a = (const float*)d_in[9];
    const float* W_l1b = (const float*)d_in[10];
    const float* g_l1b = (const float*)d_in[11];
    const float* b_l1b = (const float*)d_in[12];
    const float* W_l2a = (const float*)d_in[13];
    const float* g_l2a = (const float*)d_in[14];
    const float* b_l2a = (const float*)d_in[15];
    const float* W_l2b = (const float*)d_in[16];
    const float* g_l2b = (const float*)d_in[17];
    const float* b_l2b = (const float*)d_in[18];

    float* ws   = (float*)d_ws;
    int*   idx  = (int*)(ws + OFF_IDX);
    float* y1   = ws + OFF_Y1;
    float* y2   = ws + OFF_Y2;
    u16*   u    = (u16*)(ws + OFF_U);
    u16*   v    = (u16*)(ws + OFF_V);
    float* f2   = ws + OFF_F2;
    float* pS   = ws + OFF_PS;
    float* pS2  = ws + OFF_PS2;
    float* ab   = ws + OFF_AB;
    float *a_e1 = ab,        *be1 = ab + 128,
          *a_e2 = ab + 256,  *be2 = ab + 384,
          *a_1a = ab + 512,  *b_1a = ab + 640,
          *a_1b = ab + 768,  *b_1b = ab + 896,
          *a_2a = ab + 1024, *b_2a = ab + 1152,
          *a_2b = ab + 1280, *b_2b = ab + 1408;

    knn_kernel<<<dim3(MM/4), dim3(256), 0, stream>>>(x, idx);

    enc1_kernel<<<dim3(MM*64/256), dim3(256), 0, stream>>>(x, W_e1, y1);
    colstats_kernel<<<dim3(64), dim3(256), 0, stream>>>(y1, MM, 64, g_e1, b_e1, a_e1, be1);
    enc2_kernel<<<dim3(MM*64/256), dim3(256), 0, stream>>>(y1, a_e1, be1, W_e2, y2);
    colstats_kernel<<<dim3(64), dim3(256), 0, stream>>>(y2, MM, 64, g_e2, b_e2, a_e2, be2);

    // ---- local_op 1 ----
    uv_kernel<64, true><<<dim3(MM/32), dim3(256), 0, stream>>>(y2, a_e2, be2, W_l1a, u, v);
    estats_kernel<<<dim3(LL/256), dim3(256), 0, stream>>>(u, v, idx, pS, pS2);
    reduce_ab_kernel<<<dim3(128), dim3(256), 0, stream>>>(pS, pS2, LL/256, (float)LL, g_l1a, b_l1a, a_1a, b_1a);
    local_mfma_kernel<true><<<dim3(MM/8), dim3(256), 0, stream>>>(u, v, idx, a_1a, b_1a, W_l1b,
                                                                  nullptr, nullptr, pS, pS2, nullptr);
    reduce_ab_kernel<<<dim3(128), dim3(256), 0, stream>>>(pS, pS2, MM/8, (float)LL, g_l1b, b_l1b, a_1b, b_1b);
    local_mfma_kernel<false><<<dim3(MM/8), dim3(256), 0, stream>>>(u, v, idx, a_1a, b_1a, W_l1b,
                                                                   a_1b, b_1b, nullptr, nullptr, f2);

    // ---- local_op 2 ----
    uv_kernel<128, false><<<dim3(MM/32), dim3(256), 0, stream>>>(f2, nullptr, nullptr, W_l2a, u, v);
    estats_kernel<<<dim3(LL/256), dim3(256), 0, stream>>>(u, v, idx, pS, pS2);
    reduce_ab_kernel<<<dim3(128), dim3(256), 0, stream>>>(pS, pS2, LL/256, (float)LL, g_l2a, b_l2a, a_2a, b_2a);
    local_mfma_kernel<true><<<dim3(MM/8), dim3(256), 0, stream>>>(u, v, idx, a_2a, b_2a, W_l2b,
                                                                  nullptr, nullptr, pS, pS2, nullptr);
    reduce_ab_kernel<<<dim3(128), dim3(256), 0, stream>>>(pS, pS2, MM/8, (float)LL, g_l2b, b_l2b, a_2b, b_2b);
    local_mfma_kernel<false><<<dim3(MM/8), dim3(256), 0, stream>>>(u, v, idx, a_2a, b_2a, W_l2b,
                                                                   a_2b, b_2b, nullptr, nullptr, (float*)d_out);
}

// Round 7
// 430.604 us; speedup vs baseline: 9.6282x; 1.2222x over previous
//
#include <hip/hip_runtime.h>
#include <stdint.h>
#include <math.h>

#define BB 8
#define NN 2048
#define KK 32
#define MM (BB*NN)      // 16384 points total
#define LL (MM*KK)      // 524288 gathered rows
#define NBLK 2048       // partial-stat blocks (estats grid == local grid == 2048)
static constexpr float EPS = 1e-5f;

typedef short  short4v __attribute__((ext_vector_type(4)));
typedef short  short8v __attribute__((ext_vector_type(8)));
typedef float  f32x4   __attribute__((ext_vector_type(4)));
typedef unsigned int u32;
typedef unsigned long long u64;
typedef unsigned short u16;

__device__ inline short f2bf(float f) {   // RNE float->bf16
    unsigned u = __float_as_uint(f);
    u += 0x7fffu + ((u >> 16) & 1u);
    return (short)(u >> 16);
}

// wave64 u32 min-reduce via DPP (row_shr 1/2/4/8, row_bcast 15/31), result
// broadcast to all lanes through readlane(63).
__device__ inline u32 dpp_min_bcast_u32(u32 v) {
    u32 t;
    t = (u32)__builtin_amdgcn_update_dpp((int)v, (int)v, 0x111, 0xf, 0xf, false); v = t < v ? t : v;
    t = (u32)__builtin_amdgcn_update_dpp((int)v, (int)v, 0x112, 0xf, 0xf, false); v = t < v ? t : v;
    t = (u32)__builtin_amdgcn_update_dpp((int)v, (int)v, 0x114, 0xf, 0xf, false); v = t < v ? t : v;
    t = (u32)__builtin_amdgcn_update_dpp((int)v, (int)v, 0x118, 0xf, 0xf, false); v = t < v ? t : v;
    t = (u32)__builtin_amdgcn_update_dpp((int)v, (int)v, 0x142, 0xf, 0xf, false); v = t < v ? t : v;
    t = (u32)__builtin_amdgcn_update_dpp((int)v, (int)v, 0x143, 0xf, 0xf, false); v = t < v ? t : v;
    return (u32)__builtin_amdgcn_readlane((int)v, 63);
}

// ---------------- workspace layout (float offsets; u/v regions half-used as bf16) ----
#define OFF_IDX   0                        // int[LL]
#define OFF_Y1    (LL)                     // float[MM*64]   } Y1+Y2 contiguous = M1 region
#define OFF_Y2    (OFF_Y1 + MM*64)         // float[MM*64]   } (dead after uv1)
#define OFF_U     (OFF_Y2 + MM*64)         // u16[MM*128] (in float[MM*128] region)
#define OFF_V     (OFF_U + MM*128)         // u16[MM*128]
#define OFF_F2    (OFF_V + MM*128)         // float[MM*128]; reused as M2 after uv2
#define OFF_PS    (OFF_F2 + MM*128)        // float[128*NBLK] channel-major
#define OFF_PS2   (OFF_PS + 2048*128)      // float[128*NBLK]
#define OFF_AB    (OFF_PS2 + 2048*128)     // float[1536]

// ---------------- kNN: wave-per-query, DPP top-32, per-lane min2 cache ------------
// Lane owns candidates j = s*64+lane; dist bits in a read-only LDS row; per-lane
// TWO smallest unremoved keys (dist<<32|j) in registers (k1<=k2). Per iteration:
// 2 DPP min-reduces pick the global winner (exact (dist,j) stable order); winner
// lane shifts k1<-k2. Only when a lane's k1 goes INVALID (every 2nd win of that
// lane, wave-uniform via readlane) do a 4-reduce collective rescan of its 32
// slots (masked by its 'removed' bitmask) to rebuild (k1,k2).
__global__ __launch_bounds__(256) void knn_kernel(const float* __restrict__ x,
                                                  int* __restrict__ idx_out) {
    __shared__ u32 dlds[4][64][33];   // 33.8 KB -> 4 blocks/CU; read-only after setup
    const int t    = threadIdx.x;
    const int lane = t & 63;
    const int wv   = t >> 6;
    const int q    = blockIdx.x * 4 + wv;
    const int b    = q >> 11;
    const int n    = q & (NN - 1);

    const float* xb = x + (size_t)b * NN * 3;
    const float qx = xb[n*3], qy = xb[n*3+1], qz = xb[n*3+2];
    const float sqn = qx*qx + qy*qy + qz*qz;

    u64 k1 = ~0ULL, k2 = ~0ULL;
    #pragma unroll 4
    for (int s = 0; s < 32; ++s) {
        int j = s*64 + lane;
        const float* pj = xb + j*3;
        float x0 = pj[0], x1 = pj[1], x2 = pj[2];
        float sqj = x0*x0 + x1*x1 + x2*x2;
        float dot = qx*x0 + qy*x1 + qz*x2;
        float d = sqn + sqj - 2.0f*dot;
        d = (j == n) ? 0.0f : fmaxf(d, 0.0f);
        u32 db = __float_as_uint(d);
        dlds[wv][lane][s] = db;
        u64 key = ((u64)db << 32) | (u32)j;
        if (key < k1)      { k2 = k1; k1 = key; }
        else if (key < k2) { k2 = key; }
    }

    u32 removed = 0;
    const int out_base = q * KK;
    const int gbase    = b * NN;
    const u32 rl = (u32)(lane & 31);
    #pragma unroll 1
    for (int it = 0; it < KK; ++it) {
        // winner: smallest (dist, j) over lane heads k1
        u32 d1 = (u32)(k1 >> 32);
        u32 gd = dpp_min_bcast_u32(d1);
        u32 jc = (d1 == gd) ? (u32)k1 : 0xFFFFFFFFu;
        u32 gj = dpp_min_bcast_u32(jc);
        if (lane == 0) idx_out[out_base + it] = gbase + (int)gj;
        const int wl = (int)(gj & 63u);
        const int sw = (int)(gj >> 6);
        if (lane == wl) { removed |= (1u << sw); k1 = k2; k2 = ~0ULL; }
        // wave-uniform: does winner lane need a rebuild?
        u32 hiwl = (u32)__builtin_amdgcn_readlane((int)(u32)(k1 >> 32), wl);
        if (hiwl == 0xFFFFFFFFu) {
            u32 wmask = (u32)__builtin_amdgcn_readlane((int)removed, wl);
            u32 db = dlds[wv][wl][rl];
            if ((wmask >> rl) & 1u) db = 0xFFFFFFFFu;
            u32 m1 = dpp_min_bcast_u32(db);
            u32 s1c = (db == m1) ? rl : 0xFFFFFFFFu;
            u32 s1  = dpp_min_bcast_u32(s1c);
            u32 db2 = (rl == s1) ? 0xFFFFFFFFu : db;
            u32 m2 = dpp_min_bcast_u32(db2);
            u32 s2c = (db2 == m2) ? rl : 0xFFFFFFFFu;
            u32 s2  = dpp_min_bcast_u32(s2c);
            if (lane == wl) {
                k1 = ((u64)m1 << 32) | (s1*64u + (u32)wl);
                k2 = ((u64)m2 << 32) | (s2*64u + (u32)wl);
            }
        }
    }
}

// ---------------- encoder layer 1: y1 = x @ W_e1^T  (3 -> 64) ----------------
__global__ __launch_bounds__(256) void enc1_kernel(const float* __restrict__ x,
                                                   const float* __restrict__ W,
                                                   float* __restrict__ y1) {
    __shared__ float w[192];
    if (threadIdx.x < 192) w[threadIdx.x] = W[threadIdx.x];
    __syncthreads();
    int lin = blockIdx.x*256 + threadIdx.x;
    int row = lin >> 6, d = lin & 63;
    float x0 = x[row*3], x1 = x[row*3+1], x2 = x[row*3+2];
    y1[lin] = x0*w[d*3] + x1*w[d*3+1] + x2*w[d*3+2];
}

// ---------------- per-channel BN stats over M rows -> a,b coeffs ----------------
__global__ __launch_bounds__(256) void colstats_kernel(const float* __restrict__ y,
                                                       int Mrows, int C,
                                                       const float* __restrict__ gamma,
                                                       const float* __restrict__ beta,
                                                       float* __restrict__ a_out,
                                                       float* __restrict__ b_out) {
    __shared__ float rs[256], rs2[256];
    int c = blockIdx.x;
    float s = 0.f, s2 = 0.f;
    for (int r = threadIdx.x; r < Mrows; r += 256) {
        float vv = y[r*C + c];
        s += vv; s2 += vv*vv;
    }
    rs[threadIdx.x] = s; rs2[threadIdx.x] = s2;
    __syncthreads();
    for (int off = 128; off > 0; off >>= 1) {
        if (threadIdx.x < off) {
            rs[threadIdx.x]  += rs[threadIdx.x+off];
            rs2[threadIdx.x] += rs2[threadIdx.x+off];
        }
        __syncthreads();
    }
    if (threadIdx.x == 0) {
        float mean = rs[0] / (float)Mrows;
        float var  = rs2[0] / (float)Mrows - mean*mean;
        float a = gamma[c] * rsqrtf(var + EPS);
        a_out[c] = a;
        b_out[c] = beta[c] - mean*a;
    }
}

// ---------------- encoder layer 2: y2 = relu(bn(y1)) @ W_e2^T (64 -> 64) ----------------
__global__ __launch_bounds__(256) void enc2_kernel(const float* __restrict__ y1,
                                                   const float* __restrict__ a,
                                                   const float* __restrict__ b,
                                                   const float* __restrict__ W,
                                                   float* __restrict__ y2) {
    __shared__ float wt[4096];
    __shared__ float f[256];
    for (int i = threadIdx.x; i < 4096; i += 256)
        wt[(i & 63)*64 + (i >> 6)] = W[i];
    int lin = blockIdx.x*256 + threadIdx.x;
    int c0 = threadIdx.x & 63;
    f[threadIdx.x] = fmaxf(a[c0]*y1[lin] + b[c0], 0.0f);
    __syncthreads();
    int rloc = threadIdx.x >> 6, d = threadIdx.x & 63;
    const float* fr = f + rloc*64;
    float acc = 0.f;
    #pragma unroll 8
    for (int c = 0; c < 64; ++c) acc += fr[c] * wt[c*64 + d];
    y2[lin] = acc;
}

// ---------------- u/v transform: u = f@Wl^T, v = f@(Wr-Wl)^T  (bf16 outputs) --------
template<int CIN, bool APPLY_BN>
__global__ __launch_bounds__(256) void uv_kernel(const float* __restrict__ fin,
                                                 const float* __restrict__ a,
                                                 const float* __restrict__ b,
                                                 const float* __restrict__ W,  // 128 x (2*CIN)
                                                 u16* __restrict__ u,
                                                 u16* __restrict__ v) {
    __shared__ float f[32*CIN];
    const int r0 = blockIdx.x * 32;
    for (int i = threadIdx.x; i < 32*CIN; i += 256) {
        float val = fin[r0*CIN + i];
        if (APPLY_BN) {
            int c = i & (CIN-1);
            val = fmaxf(a[c]*val + b[c], 0.0f);
        }
        f[i] = val;
    }
    __syncthreads();
    const int d  = threadIdx.x & 127;
    const int rg = threadIdx.x >> 7;   // 0..1
    float uacc[16], vacc[16];
    #pragma unroll
    for (int r = 0; r < 16; ++r) { uacc[r] = 0.f; vacc[r] = 0.f; }
    const float* wl = W + d*2*CIN;
    const float* wr = wl + CIN;
    for (int c = 0; c < CIN; ++c) {
        float wlv = wl[c];
        float wdv = wr[c] - wlv;
        #pragma unroll
        for (int r = 0; r < 16; ++r) {
            float xv = f[(rg*16 + r)*CIN + c];
            uacc[r] += xv*wlv;
            vacc[r] += xv*wdv;
        }
    }
    #pragma unroll
    for (int r = 0; r < 16; ++r) {
        int row = r0 + rg*16 + r;
        u[(size_t)row*128 + d] = (u16)f2bf(uacc[r]);
        v[(size_t)row*128 + d] = (u16)f2bf(vacc[r]);
    }
}

// ---------------- stats of e = u[idx] + v over all (b,n,k), per channel ----------------
__global__ __launch_bounds__(256) void estats_kernel(const u16* __restrict__ u,
                                                     const u16* __restrict__ v,
                                                     const int* __restrict__ idx,
                                                     float* __restrict__ pS,
                                                     float* __restrict__ pS2) {
    __shared__ float red[4][132];
    const int t = threadIdx.x;
    const int l = t & 63;
    const int g = t >> 6;
    const int c2 = l*2;
    const int row0 = blockIdx.x * 256;
    float s0=0.f, s1=0.f, q0=0.f, q1=0.f;
    for (int r = 0; r < 64; ++r) {
        int row = row0 + r*4 + g;
        int n = row >> 5;
        int j = idx[row];
        u32 uw = *(const u32*)&u[(size_t)j*128 + c2];
        u32 vw = *(const u32*)&v[(size_t)n*128 + c2];
        float e0 = __uint_as_float(uw << 16)        + __uint_as_float(vw << 16);
        float e1 = __uint_as_float(uw & 0xffff0000u) + __uint_as_float(vw & 0xffff0000u);
        s0 += e0; q0 += e0*e0;
        s1 += e1; q1 += e1*e1;
    }
    red[g][c2] = s0; red[g][c2+1] = s1;
    __syncthreads();
    if (t < 128) pS[t*NBLK + blockIdx.x] = red[0][t]+red[1][t]+red[2][t]+red[3][t];
    __syncthreads();
    red[g][c2] = q0; red[g][c2+1] = q1;
    __syncthreads();
    if (t < 128) pS2[t*NBLK + blockIdx.x] = red[0][t]+red[1][t]+red[2][t]+red[3][t];
}

// ---------------- finalize BN coeffs: 128 blocks, coalesced channel-major reads -----
__global__ __launch_bounds__(256) void reduce_ab_kernel(const float* __restrict__ pS,
                                                        const float* __restrict__ pS2,
                                                        int nblk, float count,
                                                        const float* __restrict__ gamma,
                                                        const float* __restrict__ beta,
                                                        float* __restrict__ a_out,
                                                        float* __restrict__ b_out) {
    __shared__ double rs[256], rs2[256];
    const int c = blockIdx.x;
    const int t = threadIdx.x;
    double s = 0.0, s2 = 0.0;
    for (int i = t; i < nblk; i += 256) {
        s  += (double)pS [c*NBLK + i];
        s2 += (double)pS2[c*NBLK + i];
    }
    rs[t] = s; rs2[t] = s2;
    __syncthreads();
    for (int off = 128; off > 0; off >>= 1) {
        if (t < off) { rs[t] += rs[t+off]; rs2[t] += rs2[t+off]; }
        __syncthreads();
    }
    if (t == 0) {
        double mean = rs[0] / (double)count;
        double var  = rs2[0] / (double)count - mean*mean;
        float a = gamma[c] * (float)(1.0 / sqrt(var + (double)EPS));
        a_out[c] = a;
        b_out[c] = beta[c] - (float)mean * a;
    }
}

// ---------------- local_op heavy pass: bn2 stats AND per-point max in ONE pass ------
// act[r,c] = relu(a1[c]*(u[idx[p,r],c]+v[p,c]) + b1[c]) -> bf16 LDS
// h2 = act @ W2^T via mfma_f32_16x16x32_bf16.
// Outputs: pS/pS2 (channel-major partial sums of h2) and M[p,d] = max_r h2[p,r,d].
// Final out = relu(a2*M + b2) is applied later elementwise (max/bn2 commute, a2>0).
__device__ inline u32 bnrelu_pack(u32 uw, u32 vw, float a0, float b0, float a1, float b1) {
    float e0 = __uint_as_float(uw << 16)         + __uint_as_float(vw << 16);
    float e1 = __uint_as_float(uw & 0xffff0000u) + __uint_as_float(vw & 0xffff0000u);
    float h0 = fmaxf(a0*e0 + b0, 0.f);
    float h1 = fmaxf(a1*e1 + b1, 0.f);
    return ((u32)(u16)f2bf(h1) << 16) | (u16)f2bf(h0);
}

__global__ __launch_bounds__(256, 3) void local_stats_max_kernel(
        const u16* __restrict__ u, const u16* __restrict__ v,
        const int* __restrict__ idx,
        const float* __restrict__ a1, const float* __restrict__ b1,
        const float* __restrict__ W2,          // 128x128 row-major [d][c]
        float* __restrict__ pS, float* __restrict__ pS2,
        float* __restrict__ M) {
    __shared__ short wlds[128*136];     // bf16 W2 [d][c], pad 136
    __shared__ short alds[2][32*136];   // bf16 act [r][c], double-buffered
    const int t  = threadIdx.x;
    const int l  = t & 63;
    const int w  = t >> 6;       // wave 0..3 -> output cols 32w..32w+31
    const int lr = l & 15;
    const int kg = l >> 4;       // 0..3

    for (int i = t*4; i < 16384; i += 1024) {
        float4 wv = *(const float4*)&W2[i];
        int d = i >> 7, c = i & 127;
        short4v pk;
        pk.x = f2bf(wv.x); pk.y = f2bf(wv.y); pk.z = f2bf(wv.z); pk.w = f2bf(wv.w);
        *(short4v*)&wlds[d*136 + c] = pk;
    }

    const int sr = t >> 3;          // staging row 0..31
    const int sc = (t & 7) * 16;    // staging col base (16 channels)

    float a1v[16], b1v[16];
    #pragma unroll
    for (int i = 0; i < 16; ++i) { a1v[i] = a1[sc + i]; b1v[i] = b1[sc + i]; }

    float sacc[2] = {0.f, 0.f}, s2acc[2] = {0.f, 0.f};

    const int p0 = blockIdx.x * 8;

    auto stage = [&](int p, int bi) {
        int j = idx[p*KK + sr];
        const u32* up = (const u32*)(u + (size_t)j*128 + sc);
        const u32* vp = (const u32*)(v + (size_t)p*128 + sc);
        uint4 ua = *(const uint4*)up;
        uint4 ub = *(const uint4*)(up + 4);
        uint4 va = *(const uint4*)vp;
        uint4 vb = *(const uint4*)(vp + 4);
        uint4 w0, w1;
        w0.x = bnrelu_pack(ua.x, va.x, a1v[0],  b1v[0],  a1v[1],  b1v[1]);
        w0.y = bnrelu_pack(ua.y, va.y, a1v[2],  b1v[2],  a1v[3],  b1v[3]);
        w0.z = bnrelu_pack(ua.z, va.z, a1v[4],  b1v[4],  a1v[5],  b1v[5]);
        w0.w = bnrelu_pack(ua.w, va.w, a1v[6],  b1v[6],  a1v[7],  b1v[7]);
        w1.x = bnrelu_pack(ub.x, vb.x, a1v[8],  b1v[8],  a1v[9],  b1v[9]);
        w1.y = bnrelu_pack(ub.y, vb.y, a1v[10], b1v[10], a1v[11], b1v[11]);
        w1.z = bnrelu_pack(ub.z, vb.z, a1v[12], b1v[12], a1v[13], b1v[13]);
        w1.w = bnrelu_pack(ub.w, vb.w, a1v[14], b1v[14], a1v[15], b1v[15]);
        *(uint4*)(void*)&alds[bi][sr*136 + sc]     = w0;
        *(uint4*)(void*)&alds[bi][sr*136 + sc + 8] = w1;
    };

    stage(p0, 0);
    __syncthreads();

    for (int g = 0; g < 8; ++g) {
        const int p = p0 + g;
        if (g < 7) stage(p + 1, (g + 1) & 1);
        const short* ab = alds[g & 1];
        f32x4 acc[2][2];
        #pragma unroll
        for (int rt = 0; rt < 2; ++rt)
            #pragma unroll
            for (int ct = 0; ct < 2; ++ct)
                acc[rt][ct] = (f32x4){0.f, 0.f, 0.f, 0.f};
        #pragma unroll
        for (int kk = 0; kk < 4; ++kk) {
            const int ko = kk*32 + kg*8;
            short8v a0 = *(const short8v*)&ab[lr*136 + ko];
            short8v a1f = *(const short8v*)&ab[(16 + lr)*136 + ko];
            short8v b0 = *(const short8v*)&wlds[(w*32 + lr)*136 + ko];
            short8v b1f = *(const short8v*)&wlds[(w*32 + 16 + lr)*136 + ko];
            acc[0][0] = __builtin_amdgcn_mfma_f32_16x16x32_bf16(a0,  b0,  acc[0][0], 0, 0, 0);
            acc[1][0] = __builtin_amdgcn_mfma_f32_16x16x32_bf16(a1f, b0,  acc[1][0], 0, 0, 0);
            acc[0][1] = __builtin_amdgcn_mfma_f32_16x16x32_bf16(a0,  b1f, acc[0][1], 0, 0, 0);
            acc[1][1] = __builtin_amdgcn_mfma_f32_16x16x32_bf16(a1f, b1f, acc[1][1], 0, 0, 0);
        }
        #pragma unroll
        for (int ct = 0; ct < 2; ++ct) {
            float s = 0.f, qq = 0.f;
            float m = acc[0][ct][0];
            #pragma unroll
            for (int rt = 0; rt < 2; ++rt)
                #pragma unroll
                for (int e = 0; e < 4; ++e) {
                    float h = acc[rt][ct][e];
                    s += h; qq += h*h;
                    m = fmaxf(m, h);
                }
            sacc[ct] += s; s2acc[ct] += qq;
            m = fmaxf(m, __shfl_xor(m, 16, 64));
            m = fmaxf(m, __shfl_xor(m, 32, 64));
            if (l < 16) M[(size_t)p*128 + w*32 + ct*16 + lr] = m;
        }
        __syncthreads();
    }
    #pragma unroll
    for (int ct = 0; ct < 2; ++ct) {
        float s = sacc[ct], qq = s2acc[ct];
        s  += __shfl_xor(s, 16, 64);  s  += __shfl_xor(s, 32, 64);
        qq += __shfl_xor(qq, 16, 64); qq += __shfl_xor(qq, 32, 64);
        if (l < 16) {
            pS [(w*32 + ct*16 + lr)*NBLK + blockIdx.x] = s;
            pS2[(w*32 + ct*16 + lr)*NBLK + blockIdx.x] = qq;
        }
    }
}

// ---------------- finalize: out = relu(a2*M + b2), elementwise MM x 128 -------------
__global__ __launch_bounds__(256) void finalize_kernel(const float* __restrict__ M,
                                                       const float* __restrict__ a2,
                                                       const float* __restrict__ b2,
                                                       float* __restrict__ outp) {
    int i = blockIdx.x*256 + threadIdx.x;   // float4 index over MM*32
    int c = (i & 31) * 4;
    float4 av = *(const float4*)&a2[c];
    float4 bv = *(const float4*)&b2[c];
    float4 m = ((const float4*)M)[i];
    m.x = fmaxf(av.x*m.x + bv.x, 0.f);
    m.y = fmaxf(av.y*m.y + bv.y, 0.f);
    m.z = fmaxf(av.z*m.z + bv.z, 0.f);
    m.w = fmaxf(av.w*m.w + bv.w, 0.f);
    ((float4*)outp)[i] = m;
}

// ---------------- host launcher ----------------
extern "C" void kernel_launch(void* const* d_in, const int* in_sizes, int n_in,
                              void* d_out, int out_size, void* d_ws, size_t ws_size,
                              hipStream_t stream) {
    const float* x     = (const float*)d_in[0];
    const float* W_e1  = (const float*)d_in[1];
    const float* g_e1  = (const float*)d_in[2];
    const float* b_e1  = (const float*)d_in[3];
    const float* W_e2  = (const float*)d_in[4];
    const float* g_e2  = (const float*)d_in[5];
    const float* b_e2  = (const float*)d_in[6];
    const float* W_l1a = (const float*)d_in[7];
    const float* g_l1a = (const float*)d_in[8];
    const float* b_l1a = (const float*)d_in[9];
    const float* W_l1b = (const float*)d_in[10];
    const float* g_l1b = (const float*)d_in[11];
    const float* b_l1b = (const float*)d_in[12];
    const float* W_l2a = (const float*)d_in[13];
    const float* g_l2a = (const float*)d_in[14];
    const float* b_l2a = (const float*)d_in[15];
    const float* W_l2b = (const float*)d_in[16];
    const float* g_l2b = (const float*)d_in[17];
    const float* b_l2b = (const float*)d_in[18];

    float* ws   = (float*)d_ws;
    int*   idx  = (int*)(ws + OFF_IDX);
    float* y1   = ws + OFF_Y1;
    float* y2   = ws + OFF_Y2;
    u16*   u    = (u16*)(ws + OFF_U);
    u16*   v    = (u16*)(ws + OFF_V);
    float* f2   = ws + OFF_F2;
    float* M1   = ws + OFF_Y1;     // reuses Y1+Y2 (dead after uv1)
    float* M2   = ws + OFF_F2;     // reuses F2   (dead after uv2)
    float* pS   = ws + OFF_PS;
    float* pS2  = ws + OFF_PS2;
    float* ab   = ws + OFF_AB;
    float *a_e1 = ab,        *be1 = ab + 128,
          *a_e2 = ab + 256,  *be2 = ab + 384,
          *a_1a = ab + 512,  *b_1a = ab + 640,
          *a_1b = ab + 768,  *b_1b = ab + 896,
          *a_2a = ab + 1024, *b_2a = ab + 1152,
          *a_2b = ab + 1280, *b_2b = ab + 1408;

    knn_kernel<<<dim3(MM/4), dim3(256), 0, stream>>>(x, idx);

    enc1_kernel<<<dim3(MM*64/256), dim3(256), 0, stream>>>(x, W_e1, y1);
    colstats_kernel<<<dim3(64), dim3(256), 0, stream>>>(y1, MM, 64, g_e1, b_e1, a_e1, be1);
    enc2_kernel<<<dim3(MM*64/256), dim3(256), 0, stream>>>(y1, a_e1, be1, W_e2, y2);
    colstats_kernel<<<dim3(64), dim3(256), 0, stream>>>(y2, MM, 64, g_e2, b_e2, a_e2, be2);

    // ---- local_op 1 ----
    uv_kernel<64, true><<<dim3(MM/32), dim3(256), 0, stream>>>(y2, a_e2, be2, W_l1a, u, v);
    estats_kernel<<<dim3(LL/256), dim3(256), 0, stream>>>(u, v, idx, pS, pS2);
    reduce_ab_kernel<<<dim3(128), dim3(256), 0, stream>>>(pS, pS2, LL/256, (float)LL, g_l1a, b_l1a, a_1a, b_1a);
    local_stats_max_kernel<<<dim3(MM/8), dim3(256), 0, stream>>>(u, v, idx, a_1a, b_1a, W_l1b, pS, pS2, M1);
    reduce_ab_kernel<<<dim3(128), dim3(256), 0, stream>>>(pS, pS2, MM/8, (float)LL, g_l1b, b_l1b, a_1b, b_1b);
    finalize_kernel<<<dim3(MM*32/256), dim3(256), 0, stream>>>(M1, a_1b, b_1b, f2);

    // ---- local_op 2 ----
    uv_kernel<128, false><<<dim3(MM/32), dim3(256), 0, stream>>>(f2, nullptr, nullptr, W_l2a, u, v);
    estats_kernel<<<dim3(LL/256), dim3(256), 0, stream>>>(u, v, idx, pS, pS2);
    reduce_ab_kernel<<<dim3(128), dim3(256), 0, stream>>>(pS, pS2, LL/256, (float)LL, g_l2a, b_l2a, a_2a, b_2a);
    local_stats_max_kernel<<<dim3(MM/8), dim3(256), 0, stream>>>(u, v, idx, a_2a, b_2a, W_l2b, pS, pS2, M2);
    reduce_ab_kernel<<<dim3(128), dim3(256), 0, stream>>>(pS, pS2, MM/8, (float)LL, g_l2b, b_l2b, a_2b, b_2b);
    finalize_kernel<<<dim3(MM*32/256), dim3(256), 0, stream>>>(M2, a_2b, b_2b, (float*)d_out);
}

// Round 8
// 429.627 us; speedup vs baseline: 9.6501x; 1.0023x over previous
//
#include <hip/hip_runtime.h>
#include <hip/hip_fp16.h>
#include <stdint.h>
#include <math.h>

#define BB 8
#define NN 2048
#define KK 32
#define MM (BB*NN)      // 16384 points total
#define LL (MM*KK)      // 524288 gathered rows
#define NBLK 2048       // partial-stat blocks (estats grid == local grid == 2048)
static constexpr float EPS = 1e-5f;

typedef _Float16 half8v __attribute__((ext_vector_type(8)));
typedef float  f32x4   __attribute__((ext_vector_type(4)));
typedef unsigned int u32;
typedef unsigned long long u64;
typedef unsigned short u16;

__device__ inline u16 f2h(float f) {            // f32 -> f16 bits (RNE)
    return __half_as_ushort(__float2half(f));
}
__device__ inline float2 h2f2(u32 w) {          // packed 2xf16 -> 2xf32
    __half2 h = *reinterpret_cast<__half2*>(&w);
    return __half22float2(h);
}
__device__ inline u32 f2h2(float lo, float hi) { // 2xf32 -> packed 2xf16
    __half2 h = __floats2half2_rn(lo, hi);
    return *reinterpret_cast<u32*>(&h);
}

// wave64 u32 min-reduce via DPP, result broadcast via readlane(63).
__device__ inline u32 dpp_min_bcast_u32(u32 v) {
    u32 t;
    t = (u32)__builtin_amdgcn_update_dpp((int)v, (int)v, 0x111, 0xf, 0xf, false); v = t < v ? t : v;
    t = (u32)__builtin_amdgcn_update_dpp((int)v, (int)v, 0x112, 0xf, 0xf, false); v = t < v ? t : v;
    t = (u32)__builtin_amdgcn_update_dpp((int)v, (int)v, 0x114, 0xf, 0xf, false); v = t < v ? t : v;
    t = (u32)__builtin_amdgcn_update_dpp((int)v, (int)v, 0x118, 0xf, 0xf, false); v = t < v ? t : v;
    t = (u32)__builtin_amdgcn_update_dpp((int)v, (int)v, 0x142, 0xf, 0xf, false); v = t < v ? t : v;
    t = (u32)__builtin_amdgcn_update_dpp((int)v, (int)v, 0x143, 0xf, 0xf, false); v = t < v ? t : v;
    return (u32)__builtin_amdgcn_readlane((int)v, 63);
}

// ---------------- workspace layout (float offsets; u/v regions half-used as f16) ----
#define OFF_IDX   0                        // int[LL]
#define OFF_Y1    (LL)                     // float[MM*64]   } Y1+Y2 contiguous = M1 region
#define OFF_Y2    (OFF_Y1 + MM*64)         // float[MM*64]   } (dead after uv1)
#define OFF_U     (OFF_Y2 + MM*64)         // u16[MM*128] (in float[MM*128] region)
#define OFF_V     (OFF_U + MM*128)         // u16[MM*128]
#define OFF_F2    (OFF_V + MM*128)         // float[MM*128]; M2
#define OFF_PS    (OFF_F2 + MM*128)        // float[128*NBLK] channel-major
#define OFF_PS2   (OFF_PS + 2048*128)      // float[128*NBLK]
#define OFF_AB    (OFF_PS2 + 2048*128)     // float[1536]

// ---------------- kNN: wave-per-query, DPP+ballot top-32, per-lane min2 cache -------
__global__ __launch_bounds__(256) void knn_kernel(const float* __restrict__ x,
                                                  int* __restrict__ idx_out) {
    __shared__ u32 dlds[4][64][33];   // read-only after setup
    const int t    = threadIdx.x;
    const int lane = t & 63;
    const int wv   = t >> 6;
    const int q    = blockIdx.x * 4 + wv;
    const int b    = q >> 11;
    const int n    = q & (NN - 1);

    const float* xb = x + (size_t)b * NN * 3;
    const float qx = xb[n*3], qy = xb[n*3+1], qz = xb[n*3+2];
    const float sqn = qx*qx + qy*qy + qz*qz;

    u64 k1 = ~0ULL, k2 = ~0ULL;
    #pragma unroll 4
    for (int s = 0; s < 32; ++s) {
        int j = s*64 + lane;
        const float* pj = xb + j*3;
        float x0 = pj[0], x1 = pj[1], x2 = pj[2];
        float sqj = x0*x0 + x1*x1 + x2*x2;
        float dot = qx*x0 + qy*x1 + qz*x2;
        float d = sqn + sqj - 2.0f*dot;
        d = (j == n) ? 0.0f : fmaxf(d, 0.0f);
        u32 db = __float_as_uint(d);
        dlds[wv][lane][s] = db;
        u64 key = ((u64)db << 32) | (u32)j;
        if (key < k1)      { k2 = k1; k1 = key; }
        else if (key < k2) { k2 = key; }
    }

    u32 removed = 0;
    const int out_base = q * KK;
    const int gbase    = b * NN;
    const u32 rl = (u32)(lane & 31);
    #pragma unroll 1
    for (int it = 0; it < KK; ++it) {
        u32 d1 = (u32)(k1 >> 32);
        u32 gd = dpp_min_bcast_u32(d1);
        u64 mask = __ballot(d1 == gd);
        u32 gj;
        if (__popcll(mask) == 1) {                 // unique winner lane (common case)
            int wl0 = (int)(__ffsll((long long)mask) - 1);
            gj = (u32)__builtin_amdgcn_readlane((int)(u32)k1, wl0);
        } else {                                   // exact distance tie: full (d,j) order
            u32 jc = (d1 == gd) ? (u32)k1 : 0xFFFFFFFFu;
            gj = dpp_min_bcast_u32(jc);
        }
        if (lane == 0) idx_out[out_base + it] = gbase + (int)gj;
        const int wl = (int)(gj & 63u);
        const int sw = (int)(gj >> 6);
        if (lane == wl) { removed |= (1u << sw); k1 = k2; k2 = ~0ULL; }
        u32 hiwl = (u32)__builtin_amdgcn_readlane((int)(u32)(k1 >> 32), wl);
        if (hiwl == 0xFFFFFFFFu) {                 // rebuild winner lane's (k1,k2)
            u32 wmask = (u32)__builtin_amdgcn_readlane((int)removed, wl);
            u32 db = dlds[wv][wl][rl];
            if ((wmask >> rl) & 1u) db = 0xFFFFFFFFu;
            u32 m1 = dpp_min_bcast_u32(db);
            u64 bm1 = __ballot(db == m1 && lane < 32);
            u32 s1 = (u32)(__ffsll((long long)bm1) - 1);   // lowest slot = exact tie-break
            u32 db2 = (rl == s1) ? 0xFFFFFFFFu : db;
            u32 m2 = dpp_min_bcast_u32(db2);
            u64 bm2 = __ballot(db2 == m2 && lane < 32);
            u32 s2 = (u32)(__ffsll((long long)bm2) - 1);
            if (lane == wl) {
                k1 = ((u64)m1 << 32) | (s1*64u + (u32)wl);
                k2 = ((u64)m2 << 32) | (s2*64u + (u32)wl);
            }
        }
    }
}

// ---------------- encoder layer 1: y1 = x @ W_e1^T  (3 -> 64) ----------------
__global__ __launch_bounds__(256) void enc1_kernel(const float* __restrict__ x,
                                                   const float* __restrict__ W,
                                                   float* __restrict__ y1) {
    __shared__ float w[192];
    if (threadIdx.x < 192) w[threadIdx.x] = W[threadIdx.x];
    __syncthreads();
    int lin = blockIdx.x*256 + threadIdx.x;
    int row = lin >> 6, d = lin & 63;
    float x0 = x[row*3], x1 = x[row*3+1], x2 = x[row*3+2];
    y1[lin] = x0*w[d*3] + x1*w[d*3+1] + x2*w[d*3+2];
}

// ---------------- per-channel BN stats over M rows -> a,b coeffs ----------------
__global__ __launch_bounds__(256) void colstats_kernel(const float* __restrict__ y,
                                                       int Mrows, int C,
                                                       const float* __restrict__ gamma,
                                                       const float* __restrict__ beta,
                                                       float* __restrict__ a_out,
                                                       float* __restrict__ b_out) {
    __shared__ float rs[256], rs2[256];
    int c = blockIdx.x;
    float s = 0.f, s2 = 0.f;
    for (int r = threadIdx.x; r < Mrows; r += 256) {
        float vv = y[r*C + c];
        s += vv; s2 += vv*vv;
    }
    rs[threadIdx.x] = s; rs2[threadIdx.x] = s2;
    __syncthreads();
    for (int off = 128; off > 0; off >>= 1) {
        if (threadIdx.x < off) {
            rs[threadIdx.x]  += rs[threadIdx.x+off];
            rs2[threadIdx.x] += rs2[threadIdx.x+off];
        }
        __syncthreads();
    }
    if (threadIdx.x == 0) {
        float mean = rs[0] / (float)Mrows;
        float var  = rs2[0] / (float)Mrows - mean*mean;
        float a = gamma[c] * rsqrtf(var + EPS);
        a_out[c] = a;
        b_out[c] = beta[c] - mean*a;
    }
}

// ---------------- encoder layer 2: y2 = relu(bn(y1)) @ W_e2^T (64 -> 64) ----------------
__global__ __launch_bounds__(256) void enc2_kernel(const float* __restrict__ y1,
                                                   const float* __restrict__ a,
                                                   const float* __restrict__ b,
                                                   const float* __restrict__ W,
                                                   float* __restrict__ y2) {
    __shared__ float wt[4096];
    __shared__ float f[256];
    for (int i = threadIdx.x; i < 4096; i += 256)
        wt[(i & 63)*64 + (i >> 6)] = W[i];
    int lin = blockIdx.x*256 + threadIdx.x;
    int c0 = threadIdx.x & 63;
    f[threadIdx.x] = fmaxf(a[c0]*y1[lin] + b[c0], 0.0f);
    __syncthreads();
    int rloc = threadIdx.x >> 6, d = threadIdx.x & 63;
    const float* fr = f + rloc*64;
    float acc = 0.f;
    #pragma unroll 8
    for (int c = 0; c < 64; ++c) acc += fr[c] * wt[c*64 + d];
    y2[lin] = acc;
}

// ---------------- uv via MFMA f16: [u|v] = bnrelu?(fin) @ [Wl; Wr-Wl]^T -------------
// fin: f32 [MM][CIN]; W: f32 [128][2*CIN]; outputs u,v: f16 [MM][128].
// APPLY_BN fuses val = relu(a[c]*val + b[c]) on the A-load (encoder bn or local_op
// finalize - both have this exact form).
template<int CIN, bool APPLY_BN>
__global__ __launch_bounds__(256) void uv_mfma_kernel(
        const float* __restrict__ fin,
        const float* __restrict__ a, const float* __restrict__ b,
        const float* __restrict__ W,
        u16* __restrict__ u, u16* __restrict__ v) {
    constexpr int PAD = CIN + 8;
    __shared__ u16 wlds[256*PAD];
    __shared__ u16 alds[32*PAD];
    const int t  = threadIdx.x;
    const int l  = t & 63;
    const int w  = t >> 6;      // wave -> output cols 64w..64w+63
    const int lr = l & 15;
    const int kg = l >> 4;

    // stage W' = [Wl; Wr-Wl] as f16 (coalesced in c)
    for (int i = t; i < 256*CIN; i += 256) {
        int d = i / CIN, c = i & (CIN-1);
        float val;
        if (d < 128) val = W[d*2*CIN + c];
        else         val = W[(d-128)*2*CIN + CIN + c] - W[(d-128)*2*CIN + c];
        wlds[d*PAD + c] = f2h(val);
    }
    // stage A tile (32 rows)
    const int r0 = blockIdx.x * 32;
    for (int i = t; i < 32*CIN; i += 256) {
        int r = i / CIN, c = i & (CIN-1);
        float val = fin[(size_t)(r0 + r)*CIN + c];
        if (APPLY_BN) val = fmaxf(a[c]*val + b[c], 0.f);
        alds[r*PAD + c] = f2h(val);
    }
    __syncthreads();

    f32x4 acc[2][4];
    #pragma unroll
    for (int rt = 0; rt < 2; ++rt)
        #pragma unroll
        for (int ct = 0; ct < 4; ++ct)
            acc[rt][ct] = (f32x4){0.f, 0.f, 0.f, 0.f};
    #pragma unroll
    for (int kk = 0; kk < CIN/32; ++kk) {
        const int ko = kk*32 + kg*8;
        half8v a0 = *(const half8v*)&alds[lr*PAD + ko];
        half8v a1 = *(const half8v*)&alds[(16 + lr)*PAD + ko];
        #pragma unroll
        for (int ct = 0; ct < 4; ++ct) {
            half8v bv = *(const half8v*)&wlds[(w*64 + ct*16 + lr)*PAD + ko];
            acc[0][ct] = __builtin_amdgcn_mfma_f32_16x16x32_f16(a0, bv, acc[0][ct], 0, 0, 0);
            acc[1][ct] = __builtin_amdgcn_mfma_f32_16x16x32_f16(a1, bv, acc[1][ct], 0, 0, 0);
        }
    }
    // write: C layout col=l&15, row=(l>>4)*4+e  [m89-verified]
    #pragma unroll
    for (int rt = 0; rt < 2; ++rt) {
        #pragma unroll
        for (int ct = 0; ct < 4; ++ct) {
            int col = w*64 + ct*16 + lr;            // wave-uniform side of 128 split
            u16* dst = (col < 128) ? u : v;
            int cc = col & 127;
            #pragma unroll
            for (int e = 0; e < 4; ++e) {
                int row = r0 + rt*16 + kg*4 + e;
                dst[(size_t)row*128 + cc] = f2h(acc[rt][ct][e]);
            }
        }
    }
}

// ---------------- stats of e = u[idx] + v over all (b,n,k), per channel (f16 in) ----
__global__ __launch_bounds__(256) void estats_kernel(const u16* __restrict__ u,
                                                     const u16* __restrict__ v,
                                                     const int* __restrict__ idx,
                                                     float* __restrict__ pS,
                                                     float* __restrict__ pS2) {
    __shared__ float red[4][132];
    const int t = threadIdx.x;
    const int l = t & 63;
    const int g = t >> 6;
    const int c2 = l*2;
    const int row0 = blockIdx.x * 256;
    float s0=0.f, s1=0.f, q0=0.f, q1=0.f;
    for (int r = 0; r < 64; ++r) {
        int row = row0 + r*4 + g;
        int n = row >> 5;
        int j = idx[row];
        u32 uw = *(const u32*)&u[(size_t)j*128 + c2];
        u32 vw = *(const u32*)&v[(size_t)n*128 + c2];
        float2 uf = h2f2(uw), vf = h2f2(vw);
        float e0 = uf.x + vf.x;
        float e1 = uf.y + vf.y;
        s0 += e0; q0 += e0*e0;
        s1 += e1; q1 += e1*e1;
    }
    red[g][c2] = s0; red[g][c2+1] = s1;
    __syncthreads();
    if (t < 128) pS[t*NBLK + blockIdx.x] = red[0][t]+red[1][t]+red[2][t]+red[3][t];
    __syncthreads();
    red[g][c2] = q0; red[g][c2+1] = q1;
    __syncthreads();
    if (t < 128) pS2[t*NBLK + blockIdx.x] = red[0][t]+red[1][t]+red[2][t]+red[3][t];
}

// ---------------- finalize BN coeffs: 128 blocks, coalesced channel-major reads -----
__global__ __launch_bounds__(256) void reduce_ab_kernel(const float* __restrict__ pS,
                                                        const float* __restrict__ pS2,
                                                        int nblk, float count,
                                                        const float* __restrict__ gamma,
                                                        const float* __restrict__ beta,
                                                        float* __restrict__ a_out,
                                                        float* __restrict__ b_out) {
    __shared__ double rs[256], rs2[256];
    const int c = blockIdx.x;
    const int t = threadIdx.x;
    double s = 0.0, s2 = 0.0;
    for (int i = t; i < nblk; i += 256) {
        s  += (double)pS [c*NBLK + i];
        s2 += (double)pS2[c*NBLK + i];
    }
    rs[t] = s; rs2[t] = s2;
    __syncthreads();
    for (int off = 128; off > 0; off >>= 1) {
        if (t < off) { rs[t] += rs[t+off]; rs2[t] += rs2[t+off]; }
        __syncthreads();
    }
    if (t == 0) {
        double mean = rs[0] / (double)count;
        double var  = rs2[0] / (double)count - mean*mean;
        float a = gamma[c] * (float)(1.0 / sqrt(var + (double)EPS));
        a_out[c] = a;
        b_out[c] = beta[c] - (float)mean * a;
    }
}

// ---------------- local_op heavy pass: bn2 stats AND per-point max in ONE pass ------
__device__ inline u32 bnrelu_pack(u32 uw, u32 vw, float a0, float b0, float a1, float b1) {
    float2 uf = h2f2(uw), vf = h2f2(vw);
    float h0 = fmaxf(a0*(uf.x + vf.x) + b0, 0.f);
    float h1 = fmaxf(a1*(uf.y + vf.y) + b1, 0.f);
    return f2h2(h0, h1);
}

__global__ __launch_bounds__(256, 3) void local_stats_max_kernel(
        const u16* __restrict__ u, const u16* __restrict__ v,
        const int* __restrict__ idx,
        const float* __restrict__ a1, const float* __restrict__ b1,
        const float* __restrict__ W2,          // 128x128 row-major [d][c]
        float* __restrict__ pS, float* __restrict__ pS2,
        float* __restrict__ M) {
    __shared__ u16 wlds[128*136];     // f16 W2 [d][c], pad 136
    __shared__ u16 alds[2][32*136];   // f16 act [r][c], double-buffered
    const int t  = threadIdx.x;
    const int l  = t & 63;
    const int w  = t >> 6;       // wave 0..3 -> output cols 32w..32w+31
    const int lr = l & 15;
    const int kg = l >> 4;       // 0..3

    for (int i = t*4; i < 16384; i += 1024) {
        float4 wv = *(const float4*)&W2[i];
        int d = i >> 7, c = i & 127;
        u32* dst = (u32*)&wlds[d*136 + c];
        dst[0] = f2h2(wv.x, wv.y);
        dst[1] = f2h2(wv.z, wv.w);
    }

    const int sr = t >> 3;          // staging row 0..31
    const int sc = (t & 7) * 16;    // staging col base (16 channels)

    float a1v[16], b1v[16];
    #pragma unroll
    for (int i = 0; i < 16; ++i) { a1v[i] = a1[sc + i]; b1v[i] = b1[sc + i]; }

    float sacc[2] = {0.f, 0.f}, s2acc[2] = {0.f, 0.f};

    const int p0 = blockIdx.x * 8;

    auto stage = [&](int p, int bi) {
        int j = idx[p*KK + sr];
        const u32* up = (const u32*)(u + (size_t)j*128 + sc);
        const u32* vp = (const u32*)(v + (size_t)p*128 + sc);
        uint4 ua = *(const uint4*)up;
        uint4 ub = *(const uint4*)(up + 4);
        uint4 va = *(const uint4*)vp;
        uint4 vb = *(const uint4*)(vp + 4);
        uint4 w0, w1;
        w0.x = bnrelu_pack(ua.x, va.x, a1v[0],  b1v[0],  a1v[1],  b1v[1]);
        w0.y = bnrelu_pack(ua.y, va.y, a1v[2],  b1v[2],  a1v[3],  b1v[3]);
        w0.z = bnrelu_pack(ua.z, va.z, a1v[4],  b1v[4],  a1v[5],  b1v[5]);
        w0.w = bnrelu_pack(ua.w, va.w, a1v[6],  b1v[6],  a1v[7],  b1v[7]);
        w1.x = bnrelu_pack(ub.x, vb.x, a1v[8],  b1v[8],  a1v[9],  b1v[9]);
        w1.y = bnrelu_pack(ub.y, vb.y, a1v[10], b1v[10], a1v[11], b1v[11]);
        w1.z = bnrelu_pack(ub.z, vb.z, a1v[12], b1v[12], a1v[13], b1v[13]);
        w1.w = bnrelu_pack(ub.w, vb.w, a1v[14], b1v[14], a1v[15], b1v[15]);
        *(uint4*)(void*)&alds[bi][sr*136 + sc]     = w0;
        *(uint4*)(void*)&alds[bi][sr*136 + sc + 8] = w1;
    };

    stage(p0, 0);
    __syncthreads();

    for (int g = 0; g < 8; ++g) {
        const int p = p0 + g;
        if (g < 7) stage(p + 1, (g + 1) & 1);
        const u16* ab = alds[g & 1];
        f32x4 acc[2][2];
        #pragma unroll
        for (int rt = 0; rt < 2; ++rt)
            #pragma unroll
            for (int ct = 0; ct < 2; ++ct)
                acc[rt][ct] = (f32x4){0.f, 0.f, 0.f, 0.f};
        #pragma unroll
        for (int kk = 0; kk < 4; ++kk) {
            const int ko = kk*32 + kg*8;
            half8v a0  = *(const half8v*)&ab[lr*136 + ko];
            half8v a1f = *(const half8v*)&ab[(16 + lr)*136 + ko];
            half8v b0  = *(const half8v*)&wlds[(w*32 + lr)*136 + ko];
            half8v b1f = *(const half8v*)&wlds[(w*32 + 16 + lr)*136 + ko];
            acc[0][0] = __builtin_amdgcn_mfma_f32_16x16x32_f16(a0,  b0,  acc[0][0], 0, 0, 0);
            acc[1][0] = __builtin_amdgcn_mfma_f32_16x16x32_f16(a1f, b0,  acc[1][0], 0, 0, 0);
            acc[0][1] = __builtin_amdgcn_mfma_f32_16x16x32_f16(a0,  b1f, acc[0][1], 0, 0, 0);
            acc[1][1] = __builtin_amdgcn_mfma_f32_16x16x32_f16(a1f, b1f, acc[1][1], 0, 0, 0);
        }
        #pragma unroll
        for (int ct = 0; ct < 2; ++ct) {
            float s = 0.f, qq = 0.f;
            float m = acc[0][ct][0];
            #pragma unroll
            for (int rt = 0; rt < 2; ++rt)
                #pragma unroll
                for (int e = 0; e < 4; ++e) {
                    float h = acc[rt][ct][e];
                    s += h; qq += h*h;
                    m = fmaxf(m, h);
                }
            sacc[ct] += s; s2acc[ct] += qq;
            m = fmaxf(m, __shfl_xor(m, 16, 64));
            m = fmaxf(m, __shfl_xor(m, 32, 64));
            if (l < 16) M[(size_t)p*128 + w*32 + ct*16 + lr] = m;
        }
        __syncthreads();
    }
    #pragma unroll
    for (int ct = 0; ct < 2; ++ct) {
        float s = sacc[ct], qq = s2acc[ct];
        s  += __shfl_xor(s, 16, 64);  s  += __shfl_xor(s, 32, 64);
        qq += __shfl_xor(qq, 16, 64); qq += __shfl_xor(qq, 32, 64);
        if (l < 16) {
            pS [(w*32 + ct*16 + lr)*NBLK + blockIdx.x] = s;
            pS2[(w*32 + ct*16 + lr)*NBLK + blockIdx.x] = qq;
        }
    }
}

// ---------------- finalize: out = relu(a2*M + b2), elementwise MM x 128 -------------
__global__ __launch_bounds__(256) void finalize_kernel(const float* __restrict__ M,
                                                       const float* __restrict__ a2,
                                                       const float* __restrict__ b2,
                                                       float* __restrict__ outp) {
    int i = blockIdx.x*256 + threadIdx.x;   // float4 index over MM*32
    int c = (i & 31) * 4;
    float4 av = *(const float4*)&a2[c];
    float4 bv = *(const float4*)&b2[c];
    float4 m = ((const float4*)M)[i];
    m.x = fmaxf(av.x*m.x + bv.x, 0.f);
    m.y = fmaxf(av.y*m.y + bv.y, 0.f);
    m.z = fmaxf(av.z*m.z + bv.z, 0.f);
    m.w = fmaxf(av.w*m.w + bv.w, 0.f);
    ((float4*)outp)[i] = m;
}

// ---------------- host launcher ----------------
extern "C" void kernel_launch(void* const* d_in, const int* in_sizes, int n_in,
                              void* d_out, int out_size, void* d_ws, size_t ws_size,
                              hipStream_t stream) {
    const float* x     = (const float*)d_in[0];
    const float* W_e1  = (const float*)d_in[1];
    const float* g_e1  = (const float*)d_in[2];
    const float* b_e1  = (const float*)d_in[3];
    const float* W_e2  = (const float*)d_in[4];
    const float* g_e2  = (const float*)d_in[5];
    const float* b_e2  = (const float*)d_in[6];
    const float* W_l1a = (const float*)d_in[7];
    const float* g_l1a = (const float*)d_in[8];
    const float* b_l1a = (const float*)d_in[9];
    const float* W_l1b = (const float*)d_in[10];
    const float* g_l1b = (const float*)d_in[11];
    const float* b_l1b = (const float*)d_in[12];
    const float* W_l2a = (const float*)d_in[13];
    const float* g_l2a = (const float*)d_in[14];
    const float* b_l2a = (const float*)d_in[15];
    const float* W_l2b = (const float*)d_in[16];
    const float* g_l2b = (const float*)d_in[17];
    const float* b_l2b = (const float*)d_in[18];

    float* ws   = (float*)d_ws;
    int*   idx  = (int*)(ws + OFF_IDX);
    float* y1   = ws + OFF_Y1;
    float* y2   = ws + OFF_Y2;
    u16*   u    = (u16*)(ws + OFF_U);
    u16*   v    = (u16*)(ws + OFF_V);
    float* M1   = ws + OFF_Y1;     // reuses Y1+Y2 (dead after uv1)
    float* M2   = ws + OFF_F2;
    float* pS   = ws + OFF_PS;
    float* pS2  = ws + OFF_PS2;
    float* ab   = ws + OFF_AB;
    float *a_e1 = ab,        *be1 = ab + 128,
          *a_e2 = ab + 256,  *be2 = ab + 384,
          *a_1a = ab + 512,  *b_1a = ab + 640,
          *a_1b = ab + 768,  *b_1b = ab + 896,
          *a_2a = ab + 1024, *b_2a = ab + 1152,
          *a_2b = ab + 1280, *b_2b = ab + 1408;

    knn_kernel<<<dim3(MM/4), dim3(256), 0, stream>>>(x, idx);

    enc1_kernel<<<dim3(MM*64/256), dim3(256), 0, stream>>>(x, W_e1, y1);
    colstats_kernel<<<dim3(64), dim3(256), 0, stream>>>(y1, MM, 64, g_e1, b_e1, a_e1, be1);
    enc2_kernel<<<dim3(MM*64/256), dim3(256), 0, stream>>>(y1, a_e1, be1, W_e2, y2);
    colstats_kernel<<<dim3(64), dim3(256), 0, stream>>>(y2, MM, 64, g_e2, b_e2, a_e2, be2);

    // ---- local_op 1 ----
    uv_mfma_kernel<64, true><<<dim3(MM/32), dim3(256), 0, stream>>>(y2, a_e2, be2, W_l1a, u, v);
    estats_kernel<<<dim3(LL/256), dim3(256), 0, stream>>>(u, v, idx, pS, pS2);
    reduce_ab_kernel<<<dim3(128), dim3(256), 0, stream>>>(pS, pS2, LL/256, (float)LL, g_l1a, b_l1a, a_1a, b_1a);
    local_stats_max_kernel<<<dim3(MM/8), dim3(256), 0, stream>>>(u, v, idx, a_1a, b_1a, W_l1b, pS, pS2, M1);
    reduce_ab_kernel<<<dim3(128), dim3(256), 0, stream>>>(pS, pS2, MM/8, (float)LL, g_l1b, b_l1b, a_1b, b_1b);

    // ---- local_op 2 (finalize#1 fused into uv A-load) ----
    uv_mfma_kernel<128, true><<<dim3(MM/32), dim3(256), 0, stream>>>(M1, a_1b, b_1b, W_l2a, u, v);
    estats_kernel<<<dim3(LL/256), dim3(256), 0, stream>>>(u, v, idx, pS, pS2);
    reduce_ab_kernel<<<dim3(128), dim3(256), 0, stream>>>(pS, pS2, LL/256, (float)LL, g_l2a, b_l2a, a_2a, b_2a);
    local_stats_max_kernel<<<dim3(MM/8), dim3(256), 0, stream>>>(u, v, idx, a_2a, b_2a, W_l2b, pS, pS2, M2);
    reduce_ab_kernel<<<dim3(128), dim3(256), 0, stream>>>(pS, pS2, MM/8, (float)LL, g_l2b, b_l2b, a_2b, b_2b);
    finalize_kernel<<<dim3(MM*32/256), dim3(256), 0, stream>>>(M2, a_2b, b_2b, (float*)d_out);
}